// Round 15
// baseline (130.984 us; speedup 1.0000x reference)
//
#include <hip/hip_runtime.h>
#include <hip/hip_bf16.h>
#include <math.h>

#define B_ 2
#define S_ 4096
#define D_ 256
#define H_ 8
#define DFF_ 1024
#define DK_ 32

typedef __attribute__((ext_vector_type(8))) short short8;
typedef __attribute__((ext_vector_type(4))) float f32x4;
typedef __attribute__((ext_vector_type(16))) float f32x16;
typedef __attribute__((ext_vector_type(4))) int int4v;

__device__ __forceinline__ unsigned short f2bf(float f) {
  unsigned int u = __builtin_bit_cast(unsigned int, f);
  u += 0x7FFFu + ((u >> 16) & 1u);
  return (unsigned short)(u >> 16);
}

__device__ __forceinline__ float bf2f(unsigned short s) {
  unsigned int u = ((unsigned int)s) << 16;
  return __builtin_bit_cast(float, u);
}

__device__ __forceinline__ short8 u32x4_to_s8(unsigned int a, unsigned int b,
                                              unsigned int c, unsigned int d) {
  int4v v = {(int)a, (int)b, (int)c, (int)d};
  return __builtin_bit_cast(short8, v);
}

// ---------------- fused prep: weight transpose+convert, x->bf16 --------------
__global__ __launch_bounds__(256) void k_prepw(
    const float* __restrict__ Wq, const float* __restrict__ Wk,
    const float* __restrict__ Wv, const float* __restrict__ Wo,
    const float* __restrict__ W1, const float* __restrict__ W2,
    const float* __restrict__ bq, const float* __restrict__ bk,
    const float* __restrict__ bv, const float* __restrict__ x,
    unsigned short* __restrict__ WqkvT, unsigned short* __restrict__ WoT,
    unsigned short* __restrict__ W1T, unsigned short* __restrict__ W2T,
    float* __restrict__ bqkv, unsigned short* __restrict__ xb) {
  const float k2 = 0.25500525551f;  // log2(e)/sqrt(DK)
  int bx = blockIdx.x, t = threadIdx.x;
  if (bx < 768) {
    int which = bx >> 8;
    int i = ((bx & 255) << 8) | t;
    const float* W = (which == 0) ? Wq : (which == 1) ? Wk : Wv;
    int n = i >> 8, k = i & 255;
    float v = W[k * 256 + n] * ((which == 0) ? k2 : 1.0f);
    WqkvT[(size_t)(which * 256 + n) * 256 + k] = f2bf(v);
  } else if (bx < 1024) {
    int i = ((bx - 768) << 8) | t;
    int n = i >> 8, k = i & 255;
    WoT[i] = f2bf(Wo[k * 256 + n]);
  } else if (bx < 2048) {
    int i = ((bx - 1024) << 8) | t;
    int n = i >> 8, k = i & 255;
    W1T[i] = f2bf(W1[k * 1024 + n]);
  } else if (bx < 3072) {
    int i = ((bx - 2048) << 8) | t;
    int n = i >> 10, k = i & 1023;
    W2T[i] = f2bf(W2[k * 256 + n]);
  } else if (bx < 3075) {
    int i = ((bx - 3072) << 8) | t;
    if (i < 768) bqkv[i] = (i < 256) ? bq[i] * k2 : (i < 512) ? bk[i - 256] : bv[i - 512];
  } else {
    int i = (bx - 3075) * 2048 + t * 8;
    f32x4 f0 = *(const f32x4*)(x + i);
    f32x4 f1 = *(const f32x4*)(x + i + 4);
    short8 o;
#pragma unroll
    for (int e = 0; e < 4; e++) { o[e] = (short)f2bf(f0[e]); o[e + 4] = (short)f2bf(f1[e]); }
    *(short8*)(xb + i) = o;
  }
}

// ---------------- QKV GEMM with fragment-scatter epilogue --------------------
__global__ __launch_bounds__(256) void k_gemmqkv(const unsigned short* __restrict__ A,
                                                 const unsigned short* __restrict__ Bt,
                                                 const float* __restrict__ bias,
                                                 unsigned short* __restrict__ qb,
                                                 unsigned short* __restrict__ kpk,
                                                 unsigned short* __restrict__ vpk) {
  const int K = 256;
  __shared__ unsigned short Al[128][40];
  __shared__ unsigned short Bl[64][40];
  const int tid = threadIdx.x;
  const int wid = tid >> 6, lane = tid & 63;
  const int lhi = lane >> 4, llo = lane & 15;
  const int rowbase = wid * 32;
  const int bm = blockIdx.x, bn = blockIdx.y;

  f32x4 zero = {0.f, 0.f, 0.f, 0.f};
  f32x4 acc[2][4];
#pragma unroll
  for (int m = 0; m < 2; m++)
#pragma unroll
    for (int n = 0; n < 4; n++) acc[m][n] = zero;

  const int r0 = tid >> 2, c8 = (tid & 3) * 8;
  const unsigned short* A16a = A + (size_t)(bm * 128 + r0) * K + c8;
  const unsigned short* A16b = A + (size_t)(bm * 128 + r0 + 64) * K + c8;
  const unsigned short* Brow0 = Bt + (size_t)(bn * 64 + r0) * K + c8;

  for (int kb = 0; kb < K; kb += 32) {
    __syncthreads();
    *(short8*)&Al[r0][c8] = *(const short8*)(A16a + kb);
    *(short8*)&Al[r0 + 64][c8] = *(const short8*)(A16b + kb);
    *(short8*)&Bl[r0][c8] = *(const short8*)(Brow0 + kb);
    __syncthreads();
    short8 af[2], bf[4];
#pragma unroll
    for (int m = 0; m < 2; m++) af[m] = *(const short8*)&Al[rowbase + m * 16 + llo][lhi * 8];
#pragma unroll
    for (int n = 0; n < 4; n++) bf[n] = *(const short8*)&Bl[n * 16 + llo][lhi * 8];
#pragma unroll
    for (int m = 0; m < 2; m++)
#pragma unroll
      for (int n = 0; n < 4; n++)
        acc[m][n] = __builtin_amdgcn_mfma_f32_16x16x32_bf16(af[m], bf[n], acc[m][n], 0, 0, 0);
  }

  const int which = bn >> 2;  // 0=Q, 1=K, 2=V
#pragma unroll
  for (int m = 0; m < 2; m++)
#pragma unroll
    for (int n = 0; n < 4; n++)
#pragma unroll
      for (int r = 0; r < 4; r++) {
        int row = bm * 128 + rowbase + m * 16 + lhi * 4 + r;
        int gcol = bn * 64 + n * 16 + llo;
        int col0 = gcol - which * 256;
        float v = acc[m][n][r] + bias[gcol];
        unsigned short bv = f2bf(v);
        int t = row & (S_ - 1), b = row >> 12;
        int h = col0 >> 5;
        if (which == 0) {
          qb[(size_t)row * 256 + col0] = bv;
        } else if (which == 1) {
          int c5 = col0 & 31, jj = (c5 >> 4) & 1, hik = (c5 >> 3) & 1, e = c5 & 7;
          int tile = t >> 6, i = (t >> 5) & 1, l31k = t & 31;
          size_t addr = (((size_t)(b * 8 + h) * 64 + tile) * 4 + i * 2 + jj) * 512 +
                        (hik * 32 + l31k) * 8 + e;
          kpk[addr] = bv;
        } else {
          int d = col0 & 31;
          int x5 = t >> 6, j = (t >> 3) & 7, kk = t & 7;
          size_t addr = (((size_t)(b * 8 + h) * 64 + x5) * 4 + (j >> 1)) * 512 +
                        ((j & 1) * 32 + d) * 8 + kk;
          vpk[addr] = bv;
        }
      }
}

// ---------------- bf16 GEMM (FFN1): C = GELU(A @ Bt^T + bias), bf16 out ------
__global__ __launch_bounds__(256) void k_gemm1(const unsigned short* __restrict__ A,
                                               const unsigned short* __restrict__ Bt,
                                               const float* __restrict__ bias,
                                               unsigned short* __restrict__ Cout,
                                               int M, int N, int K) {
  __shared__ unsigned short Al[128][40];
  __shared__ unsigned short Bl[128][40];
  const int tid = threadIdx.x;
  const int wid = tid >> 6, lane = tid & 63;
  const int lhi = lane >> 4, llo = lane & 15;
  const int wr = wid >> 1, wc = wid & 1;
  const int rowbase = wr * 64, colbase = wc * 64;
  const int bm = blockIdx.x, bn = blockIdx.y;

  f32x4 zero = {0.f, 0.f, 0.f, 0.f};
  f32x4 acc[4][4];
#pragma unroll
  for (int m = 0; m < 4; m++)
#pragma unroll
    for (int n = 0; n < 4; n++) acc[m][n] = zero;

  const int r0 = tid >> 2, c8 = (tid & 3) * 8;
  const unsigned short* A16a = A + (size_t)(bm * 128 + r0) * K + c8;
  const unsigned short* A16b = A + (size_t)(bm * 128 + r0 + 64) * K + c8;
  const unsigned short* Brow0 = Bt + (size_t)(bn * 128 + r0) * K + c8;
  const unsigned short* Brow1 = Bt + (size_t)(bn * 128 + r0 + 64) * K + c8;

  for (int kb = 0; kb < K; kb += 32) {
    __syncthreads();
    *(short8*)&Al[r0][c8] = *(const short8*)(A16a + kb);
    *(short8*)&Al[r0 + 64][c8] = *(const short8*)(A16b + kb);
    *(short8*)&Bl[r0][c8] = *(const short8*)(Brow0 + kb);
    *(short8*)&Bl[r0 + 64][c8] = *(const short8*)(Brow1 + kb);
    __syncthreads();
    short8 af[4], bf[4];
#pragma unroll
    for (int m = 0; m < 4; m++) af[m] = *(const short8*)&Al[rowbase + m * 16 + llo][lhi * 8];
#pragma unroll
    for (int n = 0; n < 4; n++) bf[n] = *(const short8*)&Bl[colbase + n * 16 + llo][lhi * 8];
#pragma unroll
    for (int m = 0; m < 4; m++)
#pragma unroll
      for (int n = 0; n < 4; n++)
        acc[m][n] = __builtin_amdgcn_mfma_f32_16x16x32_bf16(af[m], bf[n], acc[m][n], 0, 0, 0);
  }

#pragma unroll
  for (int m = 0; m < 4; m++)
#pragma unroll
    for (int n = 0; n < 4; n++)
#pragma unroll
      for (int r = 0; r < 4; r++) {
        int row = bm * 128 + rowbase + m * 16 + lhi * 4 + r;
        int col = bn * 128 + colbase + n * 16 + llo;
        float v = acc[m][n][r] + bias[col];
        v = 0.5f * v * (1.0f + erff(v * 0.70710678118f));
        Cout[(size_t)row * N + col] = f2bf(v);
      }
}

// ---------------- GEMM + residual + LayerNorm fused, split-K-2 ---------------
template <int BASE16, int OUT32>
__global__ __launch_bounds__(512) void k_gemmln(const unsigned short* __restrict__ A,
                                                const unsigned short* __restrict__ Bt,
                                                const float* __restrict__ bias,
                                                const void* __restrict__ base,
                                                const float* __restrict__ alpha,
                                                const float* __restrict__ g,
                                                const float* __restrict__ be,
                                                void* __restrict__ y, int K) {
  __shared__ unsigned short Al[2][32][40];
  __shared__ unsigned short Bl[2][256][40];
  __shared__ float psum[32][4], psq[32][4];
  float* partial = (float*)&Bl[0][0][0];

  const int tid = threadIdx.x;
  const int w = tid >> 6, lane = tid & 63;
  const int kh = w >> 2, wc = w & 3;
  const int lhi = lane >> 4, llo = lane & 15;
  const int row0 = blockIdx.x * 32;
  const int Kh = K >> 1;

  f32x4 zero = {0.f, 0.f, 0.f, 0.f};
  f32x4 acc[2][4];
#pragma unroll
  for (int m = 0; m < 2; m++)
#pragma unroll
    for (int n = 0; n < 4; n++) acc[m][n] = zero;

  for (int kb = 0; kb < Kh; kb += 32) {
    __syncthreads();
    if (tid < 256) {
      int kh2 = tid >> 7, ra = (tid >> 2) & 31, ca = (tid & 3) * 8;
      *(short8*)&Al[kh2][ra][ca] =
          *(const short8*)(A + (size_t)(row0 + ra) * K + kh2 * Kh + kb + ca);
    }
#pragma unroll
    for (int s = 0; s < 4; s++) {
      int c = tid + s * 512;
      int kh2 = c >> 10, rb = (c >> 2) & 255, cb = (c & 3) * 8;
      *(short8*)&Bl[kh2][rb][cb] =
          *(const short8*)(Bt + (size_t)rb * K + kh2 * Kh + kb + cb);
    }
    __syncthreads();
    short8 af[2], bf[4];
#pragma unroll
    for (int m = 0; m < 2; m++) af[m] = *(const short8*)&Al[kh][m * 16 + llo][lhi * 8];
#pragma unroll
    for (int n = 0; n < 4; n++)
      bf[n] = *(const short8*)&Bl[kh][wc * 64 + n * 16 + llo][lhi * 8];
#pragma unroll
    for (int m = 0; m < 2; m++)
#pragma unroll
      for (int n = 0; n < 4; n++)
        acc[m][n] = __builtin_amdgcn_mfma_f32_16x16x32_bf16(af[m], bf[n], acc[m][n], 0, 0, 0);
  }

  __syncthreads();
  if (kh == 1) {
#pragma unroll
    for (int m = 0; m < 2; m++)
#pragma unroll
      for (int n = 0; n < 4; n++)
#pragma unroll
        for (int r = 0; r < 4; r++) {
          int lrow = m * 16 + lhi * 4 + r;
          int col = wc * 64 + n * 16 + llo;
          partial[lrow * 256 + col] = acc[m][n][r];
        }
  }
  __syncthreads();

  const float a = alpha[0];
  const unsigned short* b16 = (const unsigned short*)base;
  const float* b32 = (const float*)base;

  if (kh == 0) {
#pragma unroll
    for (int m = 0; m < 2; m++)
#pragma unroll
      for (int r = 0; r < 4; r++) {
        int lrow = m * 16 + lhi * 4 + r;
        size_t grow = (size_t)(row0 + lrow);
        float s = 0.f, q = 0.f;
#pragma unroll
        for (int n = 0; n < 4; n++) {
          int col = wc * 64 + n * 16 + llo;
          float v = acc[m][n][r] + partial[lrow * 256 + col] + bias[col];
          float xb = BASE16 ? bf2f(b16[grow * 256 + col]) : b32[grow * 256 + col];
          float rr = fmaf(a, v, xb);
          acc[m][n][r] = rr;
          s += rr;
          q = fmaf(rr, rr, q);
        }
#pragma unroll
        for (int off = 1; off < 16; off <<= 1) {
          s += __shfl_xor(s, off);
          q += __shfl_xor(q, off);
        }
        if (llo == 0) { psum[lrow][wc] = s; psq[lrow][wc] = q; }
      }
  }
  __syncthreads();

  if (kh == 0) {
#pragma unroll
    for (int m = 0; m < 2; m++)
#pragma unroll
      for (int r = 0; r < 4; r++) {
        int lrow = m * 16 + lhi * 4 + r;
        size_t grow = (size_t)(row0 + lrow);
        float S = psum[lrow][0] + psum[lrow][1] + psum[lrow][2] + psum[lrow][3];
        float Q = psq[lrow][0] + psq[lrow][1] + psq[lrow][2] + psq[lrow][3];
        float mu = S * (1.0f / 256.0f);
        float var = Q * (1.0f / 256.0f) - mu * mu;
        float rs = rsqrtf(var + 1e-5f);
#pragma unroll
        for (int n = 0; n < 4; n++) {
          int col = wc * 64 + n * 16 + llo;
          float o = (acc[m][n][r] - mu) * rs * g[col] + be[col];
          if (OUT32) ((float*)y)[grow * 256 + col] = o;
          else ((unsigned short*)y)[grow * 256 + col] = f2bf(o);
        }
      }
  }
}

// ---------------- flash attention: 8 waves = 4 q-tiles x 2 key-halves --------
// (round-11 version: proven stable across r9/r11/r12 replay validation, 62 us)
__global__ __launch_bounds__(512, 2) void k_attn(const unsigned short* __restrict__ qb,
                                                 const unsigned short* __restrict__ kpk,
                                                 const unsigned short* __restrict__ vpk,
                                                 const int* __restrict__ mask,
                                                 unsigned short* __restrict__ ctx) {
  __shared__ float accS[4][32][32];
  __shared__ float lS[4][32];
  const int tid = threadIdx.x;
  const int lane = tid & 63;
  const int w = tid >> 6;
  const int qt = w >> 1, half = w & 1;
  const int l31 = lane & 31, hi = lane >> 5;
  const int q0 = blockIdx.x * 128 + qt * 32;
  const int h = blockIdx.y, b = blockIdx.z;
  const size_t bS = (size_t)b * S_;

  const unsigned short* Qp = qb + (bS + q0 + l31) * 256 + h * DK_ + hi * 8;
  short8 qf0 = *(const short8*)Qp;
  short8 qf1 = *(const short8*)(Qp + 16);

  const size_t fragbase = ((size_t)(b * H_ + h) * 64 + half * 32) * 2048 + lane * 8;
  const unsigned short* kp = kpk + fragbase;
  const unsigned short* vp = vpk + fragbase;
  const int* mp = mask + bS + half * 2048 + lane;

  f32x16 acc, lacc;
#pragma unroll
  for (int r = 0; r < 16; r++) { acc[r] = 0.f; lacc[r] = 0.f; }
  const f32x16 zz = acc;
  short8 ones;
#pragma unroll
  for (int e = 0; e < 8; e++) ones[e] = (short)0x3F80;

  short8 kf0, kf1, kf2, kf3, vf0, vf1, vf2, vf3;
  unsigned int pk0[8], pk1[8];
  f32x16 s0, s1;

#define LDKF() { kf0 = *(const short8*)(kp); kf1 = *(const short8*)(kp + 512); \
                 kf2 = *(const short8*)(kp + 1024); kf3 = *(const short8*)(kp + 1536); kp += 2048; }
#define LDVF() { vf0 = *(const short8*)(vp); vf1 = *(const short8*)(vp + 512); \
                 vf2 = *(const short8*)(vp + 1024); vf3 = *(const short8*)(vp + 1536); vp += 2048; }
#define QKM() {                                                                  \
    s0 = __builtin_amdgcn_mfma_f32_32x32x16_bf16(kf0, qf0, zz, 0, 0, 0);         \
    s1 = __builtin_amdgcn_mfma_f32_32x32x16_bf16(kf2, qf0, zz, 0, 0, 0);         \
    s0 = __builtin_amdgcn_mfma_f32_32x32x16_bf16(kf1, qf1, s0, 0, 0, 0);         \
    s1 = __builtin_amdgcn_mfma_f32_32x32x16_bf16(kf3, qf1, s1, 0, 0, 0);         \
  }
#define EXPM(mv) {                                                               \
    unsigned long long bal = __ballot((mv) != 0);                                \
    if (__builtin_expect(bal != ~0ull, 0)) {                                     \
      _Pragma("unroll") for (int r = 0; r < 16; r++) {                           \
        int tt = (r & 3) + 8 * (r >> 2) + 4 * hi;                                \
        if (!((bal >> tt) & 1)) s0[r] = -3e38f;                                  \
        if (!((bal >> (tt + 32)) & 1)) s1[r] = -3e38f;                           \
      }                                                                          \
    }                                                                            \
    _Pragma("unroll") for (int r = 0; r < 16; r++) {                             \
      s0[r] = __builtin_amdgcn_exp2f(s0[r]);                                     \
      s1[r] = __builtin_amdgcn_exp2f(s1[r]);                                     \
    }                                                                            \
    _Pragma("unroll") for (int j = 0; j < 8; j++) {                              \
      asm("v_cvt_pk_bf16_f32 %0, %1, %2" : "=v"(pk0[j]) : "v"(s0[2*j]), "v"(s0[2*j+1])); \
      asm("v_cvt_pk_bf16_f32 %0, %1, %2" : "=v"(pk1[j]) : "v"(s1[2*j]), "v"(s1[2*j+1])); \
    }                                                                            \
  }
#define PVM() {                                                                  \
    __builtin_amdgcn_s_setprio(1);                                               \
    _Pragma("unroll") for (int kk = 0; kk < 4; kk++) {                           \
      unsigned int* pk = (kk < 2) ? pk0 : pk1;                                   \
      int base = (kk & 1) * 4;                                                   \
      auto r02 = __builtin_amdgcn_permlane32_swap(pk[base], pk[base + 2], false, false);     \
      auto r13 = __builtin_amdgcn_permlane32_swap(pk[base + 1], pk[base + 3], false, false); \
      short8 pfr = u32x4_to_s8(r02[0], r13[0], r02[1], r13[1]);                  \
      short8 vv = (kk == 0) ? vf0 : (kk == 1) ? vf1 : (kk == 2) ? vf2 : vf3;     \
      acc = __builtin_amdgcn_mfma_f32_32x32x16_bf16(pfr, vv, acc, 0, 0, 0);      \
      lacc = __builtin_amdgcn_mfma_f32_32x32x16_bf16(pfr, ones, lacc, 0, 0, 0);  \
    }                                                                            \
    __builtin_amdgcn_s_setprio(0);                                               \
  }

  // prologue: tile 0
  LDKF();
  int mvC = mp[0];
  int mvN = mp[64];
  QKM();
  LDKF();
  LDVF();
  EXPM(mvC);
  mvC = mvN;
  mvN = mp[128];

  for (int t = 1; t < 32; ++t) {
    QKM();
    LDKF();
    PVM();
    LDVF();
    EXPM(mvC);
    mvC = mvN;
    mvN = mp[(t + 2 < 32 ? t + 2 : 31) * 64];
  }
  PVM();

  // 2-way merge across key-halves (plain sums; no-max softmax)
  if (half == 1) {
#pragma unroll
    for (int r = 0; r < 16; r++) {
      int q = (r & 3) + 8 * (r >> 2) + 4 * hi;
      accS[qt][q][l31] = acc[r];
    }
    if (l31 == 0) {
#pragma unroll
      for (int r = 0; r < 16; r++) {
        int q = (r & 3) + 8 * (r >> 2) + 4 * hi;
        lS[qt][q] = lacc[r];
      }
    }
  }
  __syncthreads();
  if (half == 0) {
#pragma unroll
    for (int r = 0; r < 16; r++) {
      int q = (r & 3) + 8 * (r >> 2) + 4 * hi;
      float o = acc[r] + accS[qt][q][l31];
      float L = lacc[r] + lS[qt][q];
      ctx[(bS + q0 + q) * (size_t)D_ + h * DK_ + l31] = f2bf(o / L);
    }
  }
#undef LDKF
#undef LDVF
#undef QKM
#undef EXPM
#undef PVM
}

extern "C" void kernel_launch(void* const* d_in, const int* in_sizes, int n_in,
                              void* d_out, int out_size, void* d_ws, size_t ws_size,
                              hipStream_t stream) {
  const float* x   = (const float*)d_in[0];
  const int* mask  = (const int*)d_in[1];
  const float* Wq  = (const float*)d_in[2];
  const float* bq  = (const float*)d_in[3];
  const float* Wk  = (const float*)d_in[4];
  const float* bk  = (const float*)d_in[5];
  const float* Wv  = (const float*)d_in[6];
  const float* bv  = (const float*)d_in[7];
  const float* Wo  = (const float*)d_in[8];
  const float* bo  = (const float*)d_in[9];
  const float* W1  = (const float*)d_in[10];
  const float* b1  = (const float*)d_in[11];
  const float* W2  = (const float*)d_in[12];
  const float* b2  = (const float*)d_in[13];
  const float* g1  = (const float*)d_in[14];
  const float* be1 = (const float*)d_in[15];
  const float* g2  = (const float*)d_in[16];
  const float* be2 = (const float*)d_in[17];
  const float* a1  = (const float*)d_in[18];
  const float* a2  = (const float*)d_in[19];
  float* out = (float*)d_out;

  char* ws = (char*)d_ws;
  const size_t MB = 1024 * 1024;
  unsigned short* qb  = (unsigned short*)(ws + 0);        // 4 MB
  unsigned short* kpk = (unsigned short*)(ws + 5 * MB);   // 4 MB
  unsigned short* vpk = (unsigned short*)(ws + 10 * MB);  // 4 MB
  unsigned short* ctx = (unsigned short*)(ws + 15 * MB);  // 4 MB
  unsigned short* x1b = (unsigned short*)(ws + 19 * MB);  // 4 MB
  unsigned short* hb  = (unsigned short*)(ws + 23 * MB);  // 16 MB
  unsigned short* WqkvT = (unsigned short*)(ws + 40 * MB);               // 384 KB
  unsigned short* WoT   = (unsigned short*)(ws + 40 * MB + 512 * 1024);  // 128 KB
  unsigned short* W1T   = (unsigned short*)(ws + 41 * MB);               // 512 KB
  unsigned short* W2T   = (unsigned short*)(ws + 41 * MB + 512 * 1024);  // 512 KB
  float* bqkv           = (float*)(ws + 42 * MB);                        // 3 KB
  unsigned short* xb    = (unsigned short*)(ws + 43 * MB);               // 4 MB

  const int NTOK = B_ * S_;  // 8192

  k_prepw<<<dim3(4099), 256, 0, stream>>>(Wq, Wk, Wv, Wo, W1, W2, bq, bk, bv, x,
                                          WqkvT, WoT, W1T, W2T, bqkv, xb);

  k_gemmqkv<<<dim3(64, 12), 256, 0, stream>>>(xb, WqkvT, bqkv, qb, kpk, vpk);

  k_attn<<<dim3(S_ / 128, H_, B_), 512, 0, stream>>>(qb, kpk, vpk, mask, ctx);

  // Wo GEMM + residual(x) + LN1 -> x1b (bf16)
  k_gemmln<0, 0><<<dim3(NTOK / 32), 512, 0, stream>>>(ctx, WoT, bo, x, a1, g1, be1,
                                                      x1b, 256);

  k_gemm1<<<dim3(64, 8), 256, 0, stream>>>(x1b, W1T, b1, hb, NTOK, 1024, 256);

  // W2 GEMM + residual(x1b) + LN2 -> out (f32)
  k_gemmln<1, 1><<<dim3(NTOK / 32), 512, 0, stream>>>(hb, W2T, b2, x1b, a2, g2, be2,
                                                      out, 1024);
}

// Round 16
// 128.609 us; speedup vs baseline: 1.0185x; 1.0185x over previous
//
#include <hip/hip_runtime.h>
#include <hip/hip_bf16.h>
#include <math.h>

#define B_ 2
#define S_ 4096
#define D_ 256
#define H_ 8
#define DFF_ 1024
#define DK_ 32

typedef __attribute__((ext_vector_type(8))) short short8;
typedef __attribute__((ext_vector_type(4))) float f32x4;
typedef __attribute__((ext_vector_type(16))) float f32x16;
typedef __attribute__((ext_vector_type(4))) int int4v;

__device__ __forceinline__ unsigned short f2bf(float f) {
  unsigned int u = __builtin_bit_cast(unsigned int, f);
  u += 0x7FFFu + ((u >> 16) & 1u);
  return (unsigned short)(u >> 16);
}

__device__ __forceinline__ float bf2f(unsigned short s) {
  unsigned int u = ((unsigned int)s) << 16;
  return __builtin_bit_cast(float, u);
}

__device__ __forceinline__ short8 u32x4_to_s8(unsigned int a, unsigned int b,
                                              unsigned int c, unsigned int d) {
  int4v v = {(int)a, (int)b, (int)c, (int)d};
  return __builtin_bit_cast(short8, v);
}

// fast GELU (tanh form), NaN-safe at extremes; |err| vs exact erf-GELU < ~1e-3
__device__ __forceinline__ float gelu_fast(float v) {
  float e = __builtin_amdgcn_exp2f(v * fmaf(0.10294609f, v * v, 2.3022077f));
  float th = 1.0f - 2.0f * __builtin_amdgcn_rcpf(e + 1.0f);
  return 0.5f * v * (1.0f + th);
}

// ---------------- fused prep: LDS-tiled weight transpose+convert, x->bf16 ----
// bx [0,16) Wq(+k2) | [16,32) Wk | [32,48) Wv | [48,64) Wo | [64,128) W1 |
// [128,192) W2 | 192 bias | [193,1217) x->bf16
__global__ __launch_bounds__(256) void k_prepw(
    const float* __restrict__ Wq, const float* __restrict__ Wk,
    const float* __restrict__ Wv, const float* __restrict__ Wo,
    const float* __restrict__ W1, const float* __restrict__ W2,
    const float* __restrict__ bq, const float* __restrict__ bk,
    const float* __restrict__ bv, const float* __restrict__ x,
    unsigned short* __restrict__ WqkvT, unsigned short* __restrict__ WoT,
    unsigned short* __restrict__ W1T, unsigned short* __restrict__ W2T,
    float* __restrict__ bqkv, unsigned short* __restrict__ xb) {
  const float k2 = 0.25500525551f;  // log2(e)/sqrt(DK)
  int bx = blockIdx.x, t = threadIdx.x;

  if (bx < 192) {
    __shared__ float tile[64][65];
    const float* src;
    unsigned short* dst;
    int Ksz, Nsz, ti, tj;
    float scale = 1.0f;
    if (bx < 48) {
      int which = bx >> 4, s = bx & 15;
      src = (which == 0) ? Wq : (which == 1) ? Wk : Wv;
      dst = WqkvT + which * 65536;
      Ksz = 256; Nsz = 256; ti = s >> 2; tj = s & 3;
      if (which == 0) scale = k2;
    } else if (bx < 64) {
      int s = bx - 48;
      src = Wo; dst = WoT; Ksz = 256; Nsz = 256; ti = s >> 2; tj = s & 3;
    } else if (bx < 128) {
      int s = bx - 64;
      src = W1; dst = W1T; Ksz = 256; Nsz = 1024; ti = s >> 4; tj = s & 15;
    } else {
      int s = bx - 128;
      src = W2; dst = W2T; Ksz = 1024; Nsz = 256; ti = s >> 2; tj = s & 3;
    }
    int row0 = ti * 64, col0 = tj * 64;
    int c = t & 63, rg = t >> 6;
#pragma unroll
    for (int i = 0; i < 16; i++) {
      int rr = rg * 16 + i;
      tile[rr][c] = src[(size_t)(row0 + rr) * Nsz + col0 + c] * scale;
    }
    __syncthreads();
    int k = t & 63;
#pragma unroll
    for (int i = 0; i < 16; i++) {
      int nn = rg * 16 + i;
      dst[(size_t)(col0 + nn) * Ksz + row0 + k] = f2bf(tile[k][nn]);
    }
  } else if (bx == 192) {
#pragma unroll
    for (int j = 0; j < 3; j++) {
      int i = j * 256 + t;
      if (i < 768)
        bqkv[i] = (i < 256) ? bq[i] * k2 : (i < 512) ? bk[i - 256] : bv[i - 512];
    }
  } else {
    int i = (bx - 193) * 2048 + t * 8;
    f32x4 f0 = *(const f32x4*)(x + i);
    f32x4 f1 = *(const f32x4*)(x + i + 4);
    short8 o;
#pragma unroll
    for (int e = 0; e < 4; e++) { o[e] = (short)f2bf(f0[e]); o[e + 4] = (short)f2bf(f1[e]); }
    *(short8*)(xb + i) = o;
  }
}

// ---------------- QKV GEMM (BN=128) with fragment-scatter epilogue -----------
__global__ __launch_bounds__(256) void k_gemmqkv(const unsigned short* __restrict__ A,
                                                 const unsigned short* __restrict__ Bt,
                                                 const float* __restrict__ bias,
                                                 unsigned short* __restrict__ qb,
                                                 unsigned short* __restrict__ kpk,
                                                 unsigned short* __restrict__ vpk) {
  const int K = 256;
  __shared__ unsigned short Al[128][40];
  __shared__ unsigned short Bl[128][40];
  const int tid = threadIdx.x;
  const int wid = tid >> 6, lane = tid & 63;
  const int lhi = lane >> 4, llo = lane & 15;
  const int wr = wid >> 1, wc = wid & 1;
  const int rowbase = wr * 64, colbase = wc * 64;
  const int bm = blockIdx.x, bn = blockIdx.y;

  f32x4 zero = {0.f, 0.f, 0.f, 0.f};
  f32x4 acc[4][4];
#pragma unroll
  for (int m = 0; m < 4; m++)
#pragma unroll
    for (int n = 0; n < 4; n++) acc[m][n] = zero;

  const int r0 = tid >> 2, c8 = (tid & 3) * 8;
  const unsigned short* A16a = A + (size_t)(bm * 128 + r0) * K + c8;
  const unsigned short* A16b = A + (size_t)(bm * 128 + r0 + 64) * K + c8;
  const unsigned short* Brow0 = Bt + (size_t)(bn * 128 + r0) * K + c8;
  const unsigned short* Brow1 = Bt + (size_t)(bn * 128 + r0 + 64) * K + c8;

  for (int kb = 0; kb < K; kb += 32) {
    __syncthreads();
    *(short8*)&Al[r0][c8] = *(const short8*)(A16a + kb);
    *(short8*)&Al[r0 + 64][c8] = *(const short8*)(A16b + kb);
    *(short8*)&Bl[r0][c8] = *(const short8*)(Brow0 + kb);
    *(short8*)&Bl[r0 + 64][c8] = *(const short8*)(Brow1 + kb);
    __syncthreads();
    short8 af[4], bf[4];
#pragma unroll
    for (int m = 0; m < 4; m++) af[m] = *(const short8*)&Al[rowbase + m * 16 + llo][lhi * 8];
#pragma unroll
    for (int n = 0; n < 4; n++) bf[n] = *(const short8*)&Bl[colbase + n * 16 + llo][lhi * 8];
#pragma unroll
    for (int m = 0; m < 4; m++)
#pragma unroll
      for (int n = 0; n < 4; n++)
        acc[m][n] = __builtin_amdgcn_mfma_f32_16x16x32_bf16(af[m], bf[n], acc[m][n], 0, 0, 0);
  }

#pragma unroll
  for (int m = 0; m < 4; m++)
#pragma unroll
    for (int n = 0; n < 4; n++)
#pragma unroll
      for (int r = 0; r < 4; r++) {
        int row = bm * 128 + rowbase + m * 16 + lhi * 4 + r;
        int gcol = bn * 128 + colbase + n * 16 + llo;
        int which = gcol >> 8;  // 0=Q, 1=K, 2=V
        int col0 = gcol & 255;
        float v = acc[m][n][r] + bias[gcol];
        unsigned short bv = f2bf(v);
        int t = row & (S_ - 1), b = row >> 12;
        int h = col0 >> 5;
        if (which == 0) {
          qb[(size_t)row * 256 + col0] = bv;
        } else if (which == 1) {
          int c5 = col0 & 31, jj = (c5 >> 4) & 1, hik = (c5 >> 3) & 1, e = c5 & 7;
          int tile = t >> 6, i = (t >> 5) & 1, l31k = t & 31;
          size_t addr = (((size_t)(b * 8 + h) * 64 + tile) * 4 + i * 2 + jj) * 512 +
                        (hik * 32 + l31k) * 8 + e;
          kpk[addr] = bv;
        } else {
          int d = col0 & 31;
          int x5 = t >> 6, j = (t >> 3) & 7, kk = t & 7;
          size_t addr = (((size_t)(b * 8 + h) * 64 + x5) * 4 + (j >> 1)) * 512 +
                        ((j & 1) * 32 + d) * 8 + kk;
          vpk[addr] = bv;
        }
      }
}

// ---------------- bf16 GEMM (FFN1): C = GELU(A @ Bt^T + bias), bf16 out ------
__global__ __launch_bounds__(256) void k_gemm1(const unsigned short* __restrict__ A,
                                               const unsigned short* __restrict__ Bt,
                                               const float* __restrict__ bias,
                                               unsigned short* __restrict__ Cout,
                                               int M, int N, int K) {
  __shared__ unsigned short Al[128][40];
  __shared__ unsigned short Bl[128][40];
  const int tid = threadIdx.x;
  const int wid = tid >> 6, lane = tid & 63;
  const int lhi = lane >> 4, llo = lane & 15;
  const int wr = wid >> 1, wc = wid & 1;
  const int rowbase = wr * 64, colbase = wc * 64;
  const int bm = blockIdx.x, bn = blockIdx.y;

  f32x4 zero = {0.f, 0.f, 0.f, 0.f};
  f32x4 acc[4][4];
#pragma unroll
  for (int m = 0; m < 4; m++)
#pragma unroll
    for (int n = 0; n < 4; n++) acc[m][n] = zero;

  const int r0 = tid >> 2, c8 = (tid & 3) * 8;
  const unsigned short* A16a = A + (size_t)(bm * 128 + r0) * K + c8;
  const unsigned short* A16b = A + (size_t)(bm * 128 + r0 + 64) * K + c8;
  const unsigned short* Brow0 = Bt + (size_t)(bn * 128 + r0) * K + c8;
  const unsigned short* Brow1 = Bt + (size_t)(bn * 128 + r0 + 64) * K + c8;

  for (int kb = 0; kb < K; kb += 32) {
    __syncthreads();
    *(short8*)&Al[r0][c8] = *(const short8*)(A16a + kb);
    *(short8*)&Al[r0 + 64][c8] = *(const short8*)(A16b + kb);
    *(short8*)&Bl[r0][c8] = *(const short8*)(Brow0 + kb);
    *(short8*)&Bl[r0 + 64][c8] = *(const short8*)(Brow1 + kb);
    __syncthreads();
    short8 af[4], bf[4];
#pragma unroll
    for (int m = 0; m < 4; m++) af[m] = *(const short8*)&Al[rowbase + m * 16 + llo][lhi * 8];
#pragma unroll
    for (int n = 0; n < 4; n++) bf[n] = *(const short8*)&Bl[colbase + n * 16 + llo][lhi * 8];
#pragma unroll
    for (int m = 0; m < 4; m++)
#pragma unroll
      for (int n = 0; n < 4; n++)
        acc[m][n] = __builtin_amdgcn_mfma_f32_16x16x32_bf16(af[m], bf[n], acc[m][n], 0, 0, 0);
  }

#pragma unroll
  for (int m = 0; m < 4; m++)
#pragma unroll
    for (int n = 0; n < 4; n++)
#pragma unroll
      for (int r = 0; r < 4; r++) {
        int row = bm * 128 + rowbase + m * 16 + lhi * 4 + r;
        int col = bn * 128 + colbase + n * 16 + llo;
        float v = acc[m][n][r] + bias[col];
        Cout[(size_t)row * N + col] = f2bf(gelu_fast(v));
      }
}

// ---------------- GEMM + residual + LayerNorm fused, split-K-2 ---------------
template <int BASE16, int OUT32>
__global__ __launch_bounds__(512) void k_gemmln(const unsigned short* __restrict__ A,
                                                const unsigned short* __restrict__ Bt,
                                                const float* __restrict__ bias,
                                                const void* __restrict__ base,
                                                const float* __restrict__ alpha,
                                                const float* __restrict__ g,
                                                const float* __restrict__ be,
                                                void* __restrict__ y, int K) {
  __shared__ unsigned short Al[2][32][40];
  __shared__ unsigned short Bl[2][256][40];
  __shared__ float psum[32][4], psq[32][4];
  float* partial = (float*)&Bl[0][0][0];

  const int tid = threadIdx.x;
  const int w = tid >> 6, lane = tid & 63;
  const int kh = w >> 2, wc = w & 3;
  const int lhi = lane >> 4, llo = lane & 15;
  const int row0 = blockIdx.x * 32;
  const int Kh = K >> 1;

  f32x4 zero = {0.f, 0.f, 0.f, 0.f};
  f32x4 acc[2][4];
#pragma unroll
  for (int m = 0; m < 2; m++)
#pragma unroll
    for (int n = 0; n < 4; n++) acc[m][n] = zero;

  for (int kb = 0; kb < Kh; kb += 32) {
    __syncthreads();
    if (tid < 256) {
      int kh2 = tid >> 7, ra = (tid >> 2) & 31, ca = (tid & 3) * 8;
      *(short8*)&Al[kh2][ra][ca] =
          *(const short8*)(A + (size_t)(row0 + ra) * K + kh2 * Kh + kb + ca);
    }
#pragma unroll
    for (int s = 0; s < 4; s++) {
      int c = tid + s * 512;
      int kh2 = c >> 10, rb = (c >> 2) & 255, cb = (c & 3) * 8;
      *(short8*)&Bl[kh2][rb][cb] =
          *(const short8*)(Bt + (size_t)rb * K + kh2 * Kh + kb + cb);
    }
    __syncthreads();
    short8 af[2], bf[4];
#pragma unroll
    for (int m = 0; m < 2; m++) af[m] = *(const short8*)&Al[kh][m * 16 + llo][lhi * 8];
#pragma unroll
    for (int n = 0; n < 4; n++)
      bf[n] = *(const short8*)&Bl[kh][wc * 64 + n * 16 + llo][lhi * 8];
#pragma unroll
    for (int m = 0; m < 2; m++)
#pragma unroll
      for (int n = 0; n < 4; n++)
        acc[m][n] = __builtin_amdgcn_mfma_f32_16x16x32_bf16(af[m], bf[n], acc[m][n], 0, 0, 0);
  }

  __syncthreads();
  if (kh == 1) {
#pragma unroll
    for (int m = 0; m < 2; m++)
#pragma unroll
      for (int n = 0; n < 4; n++)
#pragma unroll
        for (int r = 0; r < 4; r++) {
          int lrow = m * 16 + lhi * 4 + r;
          int col = wc * 64 + n * 16 + llo;
          partial[lrow * 256 + col] = acc[m][n][r];
        }
  }
  __syncthreads();

  const float a = alpha[0];
  const unsigned short* b16 = (const unsigned short*)base;
  const float* b32 = (const float*)base;

  if (kh == 0) {
#pragma unroll
    for (int m = 0; m < 2; m++)
#pragma unroll
      for (int r = 0; r < 4; r++) {
        int lrow = m * 16 + lhi * 4 + r;
        size_t grow = (size_t)(row0 + lrow);
        float s = 0.f, q = 0.f;
#pragma unroll
        for (int n = 0; n < 4; n++) {
          int col = wc * 64 + n * 16 + llo;
          float v = acc[m][n][r] + partial[lrow * 256 + col] + bias[col];
          float xb = BASE16 ? bf2f(b16[grow * 256 + col]) : b32[grow * 256 + col];
          float rr = fmaf(a, v, xb);
          acc[m][n][r] = rr;
          s += rr;
          q = fmaf(rr, rr, q);
        }
#pragma unroll
        for (int off = 1; off < 16; off <<= 1) {
          s += __shfl_xor(s, off);
          q += __shfl_xor(q, off);
        }
        if (llo == 0) { psum[lrow][wc] = s; psq[lrow][wc] = q; }
      }
  }
  __syncthreads();

  if (kh == 0) {
#pragma unroll
    for (int m = 0; m < 2; m++)
#pragma unroll
      for (int r = 0; r < 4; r++) {
        int lrow = m * 16 + lhi * 4 + r;
        size_t grow = (size_t)(row0 + lrow);
        float S = psum[lrow][0] + psum[lrow][1] + psum[lrow][2] + psum[lrow][3];
        float Q = psq[lrow][0] + psq[lrow][1] + psq[lrow][2] + psq[lrow][3];
        float mu = S * (1.0f / 256.0f);
        float var = Q * (1.0f / 256.0f) - mu * mu;
        float rs = rsqrtf(var + 1e-5f);
#pragma unroll
        for (int n = 0; n < 4; n++) {
          int col = wc * 64 + n * 16 + llo;
          float o = (acc[m][n][r] - mu) * rs * g[col] + be[col];
          if (OUT32) ((float*)y)[grow * 256 + col] = o;
          else ((unsigned short*)y)[grow * 256 + col] = f2bf(o);
        }
      }
  }
}

// ---------------- flash attention: 8 waves = 4 q-tiles x 2 key-halves --------
// (round-11 version: proven stable across r9/r11/r12/r15 replay validation)
__global__ __launch_bounds__(512, 2) void k_attn(const unsigned short* __restrict__ qb,
                                                 const unsigned short* __restrict__ kpk,
                                                 const unsigned short* __restrict__ vpk,
                                                 const int* __restrict__ mask,
                                                 unsigned short* __restrict__ ctx) {
  __shared__ float accS[4][32][32];
  __shared__ float lS[4][32];
  const int tid = threadIdx.x;
  const int lane = tid & 63;
  const int w = tid >> 6;
  const int qt = w >> 1, half = w & 1;
  const int l31 = lane & 31, hi = lane >> 5;
  const int q0 = blockIdx.x * 128 + qt * 32;
  const int h = blockIdx.y, b = blockIdx.z;
  const size_t bS = (size_t)b * S_;

  const unsigned short* Qp = qb + (bS + q0 + l31) * 256 + h * DK_ + hi * 8;
  short8 qf0 = *(const short8*)Qp;
  short8 qf1 = *(const short8*)(Qp + 16);

  const size_t fragbase = ((size_t)(b * H_ + h) * 64 + half * 32) * 2048 + lane * 8;
  const unsigned short* kp = kpk + fragbase;
  const unsigned short* vp = vpk + fragbase;
  const int* mp = mask + bS + half * 2048 + lane;

  f32x16 acc, lacc;
#pragma unroll
  for (int r = 0; r < 16; r++) { acc[r] = 0.f; lacc[r] = 0.f; }
  const f32x16 zz = acc;
  short8 ones;
#pragma unroll
  for (int e = 0; e < 8; e++) ones[e] = (short)0x3F80;

  short8 kf0, kf1, kf2, kf3, vf0, vf1, vf2, vf3;
  unsigned int pk0[8], pk1[8];
  f32x16 s0, s1;

#define LDKF() { kf0 = *(const short8*)(kp); kf1 = *(const short8*)(kp + 512); \
                 kf2 = *(const short8*)(kp + 1024); kf3 = *(const short8*)(kp + 1536); kp += 2048; }
#define LDVF() { vf0 = *(const short8*)(vp); vf1 = *(const short8*)(vp + 512); \
                 vf2 = *(const short8*)(vp + 1024); vf3 = *(const short8*)(vp + 1536); vp += 2048; }
#define QKM() {                                                                  \
    s0 = __builtin_amdgcn_mfma_f32_32x32x16_bf16(kf0, qf0, zz, 0, 0, 0);         \
    s1 = __builtin_amdgcn_mfma_f32_32x32x16_bf16(kf2, qf0, zz, 0, 0, 0);         \
    s0 = __builtin_amdgcn_mfma_f32_32x32x16_bf16(kf1, qf1, s0, 0, 0, 0);         \
    s1 = __builtin_amdgcn_mfma_f32_32x32x16_bf16(kf3, qf1, s1, 0, 0, 0);         \
  }
#define EXPM(mv) {                                                               \
    unsigned long long bal = __ballot((mv) != 0);                                \
    if (__builtin_expect(bal != ~0ull, 0)) {                                     \
      _Pragma("unroll") for (int r = 0; r < 16; r++) {                           \
        int tt = (r & 3) + 8 * (r >> 2) + 4 * hi;                                \
        if (!((bal >> tt) & 1)) s0[r] = -3e38f;                                  \
        if (!((bal >> (tt + 32)) & 1)) s1[r] = -3e38f;                           \
      }                                                                          \
    }                                                                            \
    _Pragma("unroll") for (int r = 0; r < 16; r++) {                             \
      s0[r] = __builtin_amdgcn_exp2f(s0[r]);                                     \
      s1[r] = __builtin_amdgcn_exp2f(s1[r]);                                     \
    }                                                                            \
    _Pragma("unroll") for (int j = 0; j < 8; j++) {                              \
      asm("v_cvt_pk_bf16_f32 %0, %1, %2" : "=v"(pk0[j]) : "v"(s0[2*j]), "v"(s0[2*j+1])); \
      asm("v_cvt_pk_bf16_f32 %0, %1, %2" : "=v"(pk1[j]) : "v"(s1[2*j]), "v"(s1[2*j+1])); \
    }                                                                            \
  }
#define PVM() {                                                                  \
    __builtin_amdgcn_s_setprio(1);                                               \
    _Pragma("unroll") for (int kk = 0; kk < 4; kk++) {                           \
      unsigned int* pk = (kk < 2) ? pk0 : pk1;                                   \
      int base = (kk & 1) * 4;                                                   \
      auto r02 = __builtin_amdgcn_permlane32_swap(pk[base], pk[base + 2], false, false);     \
      auto r13 = __builtin_amdgcn_permlane32_swap(pk[base + 1], pk[base + 3], false, false); \
      short8 pfr = u32x4_to_s8(r02[0], r13[0], r02[1], r13[1]);                  \
      short8 vv = (kk == 0) ? vf0 : (kk == 1) ? vf1 : (kk == 2) ? vf2 : vf3;     \
      acc = __builtin_amdgcn_mfma_f32_32x32x16_bf16(pfr, vv, acc, 0, 0, 0);      \
      lacc = __builtin_amdgcn_mfma_f32_32x32x16_bf16(pfr, ones, lacc, 0, 0, 0);  \
    }                                                                            \
    __builtin_amdgcn_s_setprio(0);                                               \
  }

  // prologue: tile 0
  LDKF();
  int mvC = mp[0];
  int mvN = mp[64];
  QKM();
  LDKF();
  LDVF();
  EXPM(mvC);
  mvC = mvN;
  mvN = mp[128];

  for (int t = 1; t < 32; ++t) {
    QKM();
    LDKF();
    PVM();
    LDVF();
    EXPM(mvC);
    mvC = mvN;
    mvN = mp[(t + 2 < 32 ? t + 2 : 31) * 64];
  }
  PVM();

  // 2-way merge across key-halves (plain sums; no-max softmax)
  if (half == 1) {
#pragma unroll
    for (int r = 0; r < 16; r++) {
      int q = (r & 3) + 8 * (r >> 2) + 4 * hi;
      accS[qt][q][l31] = acc[r];
    }
    if (l31 == 0) {
#pragma unroll
      for (int r = 0; r < 16; r++) {
        int q = (r & 3) + 8 * (r >> 2) + 4 * hi;
        lS[qt][q] = lacc[r];
      }
    }
  }
  __syncthreads();
  if (half == 0) {
#pragma unroll
    for (int r = 0; r < 16; r++) {
      int q = (r & 3) + 8 * (r >> 2) + 4 * hi;
      float o = acc[r] + accS[qt][q][l31];
      float L = lacc[r] + lS[qt][q];
      ctx[(bS + q0 + q) * (size_t)D_ + h * DK_ + l31] = f2bf(o / L);
    }
  }
#undef LDKF
#undef LDVF
#undef QKM
#undef EXPM
#undef PVM
}

extern "C" void kernel_launch(void* const* d_in, const int* in_sizes, int n_in,
                              void* d_out, int out_size, void* d_ws, size_t ws_size,
                              hipStream_t stream) {
  const float* x   = (const float*)d_in[0];
  const int* mask  = (const int*)d_in[1];
  const float* Wq  = (const float*)d_in[2];
  const float* bq  = (const float*)d_in[3];
  const float* Wk  = (const float*)d_in[4];
  const float* bk  = (const float*)d_in[5];
  const float* Wv  = (const float*)d_in[6];
  const float* bv  = (const float*)d_in[7];
  const float* Wo  = (const float*)d_in[8];
  const float* bo  = (const float*)d_in[9];
  const float* W1  = (const float*)d_in[10];
  const float* b1  = (const float*)d_in[11];
  const float* W2  = (const float*)d_in[12];
  const float* b2  = (const float*)d_in[13];
  const float* g1  = (const float*)d_in[14];
  const float* be1 = (const float*)d_in[15];
  const float* g2  = (const float*)d_in[16];
  const float* be2 = (const float*)d_in[17];
  const float* a1  = (const float*)d_in[18];
  const float* a2  = (const float*)d_in[19];
  float* out = (float*)d_out;

  char* ws = (char*)d_ws;
  const size_t MB = 1024 * 1024;
  unsigned short* qb  = (unsigned short*)(ws + 0);        // 4 MB
  unsigned short* kpk = (unsigned short*)(ws + 5 * MB);   // 4 MB
  unsigned short* vpk = (unsigned short*)(ws + 10 * MB);  // 4 MB
  unsigned short* ctx = (unsigned short*)(ws + 15 * MB);  // 4 MB
  unsigned short* x1b = (unsigned short*)(ws + 19 * MB);  // 4 MB
  unsigned short* hb  = (unsigned short*)(ws + 23 * MB);  // 16 MB
  unsigned short* WqkvT = (unsigned short*)(ws + 40 * MB);               // 384 KB
  unsigned short* WoT   = (unsigned short*)(ws + 40 * MB + 512 * 1024);  // 128 KB
  unsigned short* W1T   = (unsigned short*)(ws + 41 * MB);               // 512 KB
  unsigned short* W2T   = (unsigned short*)(ws + 41 * MB + 512 * 1024);  // 512 KB
  float* bqkv           = (float*)(ws + 42 * MB);                        // 3 KB
  unsigned short* xb    = (unsigned short*)(ws + 43 * MB);               // 4 MB

  const int NTOK = B_ * S_;  // 8192

  k_prepw<<<dim3(1217), 256, 0, stream>>>(Wq, Wk, Wv, Wo, W1, W2, bq, bk, bv, x,
                                          WqkvT, WoT, W1T, W2T, bqkv, xb);

  k_gemmqkv<<<dim3(64, 6), 256, 0, stream>>>(xb, WqkvT, bqkv, qb, kpk, vpk);

  k_attn<<<dim3(S_ / 128, H_, B_), 512, 0, stream>>>(qb, kpk, vpk, mask, ctx);

  // Wo GEMM + residual(x) + LN1 -> x1b (bf16)
  k_gemmln<0, 0><<<dim3(NTOK / 32), 512, 0, stream>>>(ctx, WoT, bo, x, a1, g1, be1,
                                                      x1b, 256);

  k_gemm1<<<dim3(64, 8), 256, 0, stream>>>(x1b, W1T, b1, hb, NTOK, 1024, 256);

  // W2 GEMM + residual(x1b) + LN2 -> out (f32)
  k_gemmln<1, 1><<<dim3(NTOK / 32), 512, 0, stream>>>(hb, W2T, b2, x1b, a2, g2, be2,
                                                      out, 1024);
}

// Round 17
// 123.328 us; speedup vs baseline: 1.0621x; 1.0428x over previous
//
#include <hip/hip_runtime.h>
#include <hip/hip_bf16.h>
#include <math.h>

#define B_ 2
#define S_ 4096
#define D_ 256
#define H_ 8
#define DFF_ 1024
#define DK_ 32

typedef __attribute__((ext_vector_type(8))) short short8;
typedef __attribute__((ext_vector_type(4))) float f32x4;
typedef __attribute__((ext_vector_type(16))) float f32x16;
typedef __attribute__((ext_vector_type(4))) int int4v;

__device__ __forceinline__ unsigned short f2bf(float f) {
  unsigned int u = __builtin_bit_cast(unsigned int, f);
  u += 0x7FFFu + ((u >> 16) & 1u);
  return (unsigned short)(u >> 16);
}

__device__ __forceinline__ float bf2f(unsigned short s) {
  unsigned int u = ((unsigned int)s) << 16;
  return __builtin_bit_cast(float, u);
}

__device__ __forceinline__ short8 u32x4_to_s8(unsigned int a, unsigned int b,
                                              unsigned int c, unsigned int d) {
  int4v v = {(int)a, (int)b, (int)c, (int)d};
  return __builtin_bit_cast(short8, v);
}

// fast GELU (tanh form), NaN-safe at extremes; |err| vs exact erf-GELU < ~1e-3
__device__ __forceinline__ float gelu_fast(float v) {
  float e = __builtin_amdgcn_exp2f(v * fmaf(0.10294609f, v * v, 2.3022077f));
  float th = 1.0f - 2.0f * __builtin_amdgcn_rcpf(e + 1.0f);
  return 0.5f * v * (1.0f + th);
}

// ---------------- fused prep: LDS-tiled weight transpose+convert, x->bf16 ----
__global__ __launch_bounds__(256) void k_prepw(
    const float* __restrict__ Wq, const float* __restrict__ Wk,
    const float* __restrict__ Wv, const float* __restrict__ Wo,
    const float* __restrict__ W1, const float* __restrict__ W2,
    const float* __restrict__ bq, const float* __restrict__ bk,
    const float* __restrict__ bv, const float* __restrict__ x,
    unsigned short* __restrict__ WqkvT, unsigned short* __restrict__ WoT,
    unsigned short* __restrict__ W1T, unsigned short* __restrict__ W2T,
    float* __restrict__ bqkv, unsigned short* __restrict__ xb) {
  const float k2 = 0.25500525551f;  // log2(e)/sqrt(DK)
  int bx = blockIdx.x, t = threadIdx.x;

  if (bx < 192) {
    __shared__ float tile[64][65];
    const float* src;
    unsigned short* dst;
    int Ksz, Nsz, ti, tj;
    float scale = 1.0f;
    if (bx < 48) {
      int which = bx >> 4, s = bx & 15;
      src = (which == 0) ? Wq : (which == 1) ? Wk : Wv;
      dst = WqkvT + which * 65536;
      Ksz = 256; Nsz = 256; ti = s >> 2; tj = s & 3;
      if (which == 0) scale = k2;
    } else if (bx < 64) {
      int s = bx - 48;
      src = Wo; dst = WoT; Ksz = 256; Nsz = 256; ti = s >> 2; tj = s & 3;
    } else if (bx < 128) {
      int s = bx - 64;
      src = W1; dst = W1T; Ksz = 256; Nsz = 1024; ti = s >> 4; tj = s & 15;
    } else {
      int s = bx - 128;
      src = W2; dst = W2T; Ksz = 1024; Nsz = 256; ti = s >> 2; tj = s & 3;
    }
    int row0 = ti * 64, col0 = tj * 64;
    int c = t & 63, rg = t >> 6;
#pragma unroll
    for (int i = 0; i < 16; i++) {
      int rr = rg * 16 + i;
      tile[rr][c] = src[(size_t)(row0 + rr) * Nsz + col0 + c] * scale;
    }
    __syncthreads();
    int k = t & 63;
#pragma unroll
    for (int i = 0; i < 16; i++) {
      int nn = rg * 16 + i;
      dst[(size_t)(col0 + nn) * Ksz + row0 + k] = f2bf(tile[k][nn]);
    }
  } else if (bx == 192) {
#pragma unroll
    for (int j = 0; j < 3; j++) {
      int i = j * 256 + t;
      if (i < 768)
        bqkv[i] = (i < 256) ? bq[i] * k2 : (i < 512) ? bk[i - 256] : bv[i - 512];
    }
  } else {
    int i = (bx - 193) * 2048 + t * 8;
    f32x4 f0 = *(const f32x4*)(x + i);
    f32x4 f1 = *(const f32x4*)(x + i + 4);
    short8 o;
#pragma unroll
    for (int e = 0; e < 4; e++) { o[e] = (short)f2bf(f0[e]); o[e + 4] = (short)f2bf(f1[e]); }
    *(short8*)(xb + i) = o;
  }
}

// ---------------- QKV GEMM (BN=128) with fragment-scatter epilogue -----------
__global__ __launch_bounds__(256) void k_gemmqkv(const unsigned short* __restrict__ A,
                                                 const unsigned short* __restrict__ Bt,
                                                 const float* __restrict__ bias,
                                                 unsigned short* __restrict__ qb,
                                                 unsigned short* __restrict__ kpk,
                                                 unsigned short* __restrict__ vpk) {
  const int K = 256;
  __shared__ unsigned short Al[128][40];
  __shared__ unsigned short Bl[128][40];
  const int tid = threadIdx.x;
  const int wid = tid >> 6, lane = tid & 63;
  const int lhi = lane >> 4, llo = lane & 15;
  const int wr = wid >> 1, wc = wid & 1;
  const int rowbase = wr * 64, colbase = wc * 64;
  const int bm = blockIdx.x, bn = blockIdx.y;

  f32x4 zero = {0.f, 0.f, 0.f, 0.f};
  f32x4 acc[4][4];
#pragma unroll
  for (int m = 0; m < 4; m++)
#pragma unroll
    for (int n = 0; n < 4; n++) acc[m][n] = zero;

  const int r0 = tid >> 2, c8 = (tid & 3) * 8;
  const unsigned short* A16a = A + (size_t)(bm * 128 + r0) * K + c8;
  const unsigned short* A16b = A + (size_t)(bm * 128 + r0 + 64) * K + c8;
  const unsigned short* Brow0 = Bt + (size_t)(bn * 128 + r0) * K + c8;
  const unsigned short* Brow1 = Bt + (size_t)(bn * 128 + r0 + 64) * K + c8;

  for (int kb = 0; kb < K; kb += 32) {
    __syncthreads();
    *(short8*)&Al[r0][c8] = *(const short8*)(A16a + kb);
    *(short8*)&Al[r0 + 64][c8] = *(const short8*)(A16b + kb);
    *(short8*)&Bl[r0][c8] = *(const short8*)(Brow0 + kb);
    *(short8*)&Bl[r0 + 64][c8] = *(const short8*)(Brow1 + kb);
    __syncthreads();
    short8 af[4], bf[4];
#pragma unroll
    for (int m = 0; m < 4; m++) af[m] = *(const short8*)&Al[rowbase + m * 16 + llo][lhi * 8];
#pragma unroll
    for (int n = 0; n < 4; n++) bf[n] = *(const short8*)&Bl[colbase + n * 16 + llo][lhi * 8];
#pragma unroll
    for (int m = 0; m < 4; m++)
#pragma unroll
      for (int n = 0; n < 4; n++)
        acc[m][n] = __builtin_amdgcn_mfma_f32_16x16x32_bf16(af[m], bf[n], acc[m][n], 0, 0, 0);
  }

#pragma unroll
  for (int m = 0; m < 4; m++)
#pragma unroll
    for (int n = 0; n < 4; n++)
#pragma unroll
      for (int r = 0; r < 4; r++) {
        int row = bm * 128 + rowbase + m * 16 + lhi * 4 + r;
        int gcol = bn * 128 + colbase + n * 16 + llo;
        int which = gcol >> 8;  // 0=Q, 1=K, 2=V
        int col0 = gcol & 255;
        float v = acc[m][n][r] + bias[gcol];
        unsigned short bv = f2bf(v);
        int t = row & (S_ - 1), b = row >> 12;
        int h = col0 >> 5;
        if (which == 0) {
          qb[(size_t)row * 256 + col0] = bv;
        } else if (which == 1) {
          int c5 = col0 & 31, jj = (c5 >> 4) & 1, hik = (c5 >> 3) & 1, e = c5 & 7;
          int tile = t >> 6, i = (t >> 5) & 1, l31k = t & 31;
          size_t addr = (((size_t)(b * 8 + h) * 64 + tile) * 4 + i * 2 + jj) * 512 +
                        (hik * 32 + l31k) * 8 + e;
          kpk[addr] = bv;
        } else {
          int d = col0 & 31;
          int x5 = t >> 6, j = (t >> 3) & 7, kk = t & 7;
          size_t addr = (((size_t)(b * 8 + h) * 64 + x5) * 4 + (j >> 1)) * 512 +
                        ((j & 1) * 32 + d) * 8 + kk;
          vpk[addr] = bv;
        }
      }
}

// ---------------- bf16 GEMM (FFN1): C = GELU(A @ Bt^T + bias), bf16 out ------
__global__ __launch_bounds__(256) void k_gemm1(const unsigned short* __restrict__ A,
                                               const unsigned short* __restrict__ Bt,
                                               const float* __restrict__ bias,
                                               unsigned short* __restrict__ Cout,
                                               int M, int N, int K) {
  __shared__ unsigned short Al[128][40];
  __shared__ unsigned short Bl[128][40];
  const int tid = threadIdx.x;
  const int wid = tid >> 6, lane = tid & 63;
  const int lhi = lane >> 4, llo = lane & 15;
  const int wr = wid >> 1, wc = wid & 1;
  const int rowbase = wr * 64, colbase = wc * 64;
  const int bm = blockIdx.x, bn = blockIdx.y;

  f32x4 zero = {0.f, 0.f, 0.f, 0.f};
  f32x4 acc[4][4];
#pragma unroll
  for (int m = 0; m < 4; m++)
#pragma unroll
    for (int n = 0; n < 4; n++) acc[m][n] = zero;

  const int r0 = tid >> 2, c8 = (tid & 3) * 8;
  const unsigned short* A16a = A + (size_t)(bm * 128 + r0) * K + c8;
  const unsigned short* A16b = A + (size_t)(bm * 128 + r0 + 64) * K + c8;
  const unsigned short* Brow0 = Bt + (size_t)(bn * 128 + r0) * K + c8;
  const unsigned short* Brow1 = Bt + (size_t)(bn * 128 + r0 + 64) * K + c8;

  for (int kb = 0; kb < K; kb += 32) {
    __syncthreads();
    *(short8*)&Al[r0][c8] = *(const short8*)(A16a + kb);
    *(short8*)&Al[r0 + 64][c8] = *(const short8*)(A16b + kb);
    *(short8*)&Bl[r0][c8] = *(const short8*)(Brow0 + kb);
    *(short8*)&Bl[r0 + 64][c8] = *(const short8*)(Brow1 + kb);
    __syncthreads();
    short8 af[4], bf[4];
#pragma unroll
    for (int m = 0; m < 4; m++) af[m] = *(const short8*)&Al[rowbase + m * 16 + llo][lhi * 8];
#pragma unroll
    for (int n = 0; n < 4; n++) bf[n] = *(const short8*)&Bl[colbase + n * 16 + llo][lhi * 8];
#pragma unroll
    for (int m = 0; m < 4; m++)
#pragma unroll
      for (int n = 0; n < 4; n++)
        acc[m][n] = __builtin_amdgcn_mfma_f32_16x16x32_bf16(af[m], bf[n], acc[m][n], 0, 0, 0);
  }

#pragma unroll
  for (int m = 0; m < 4; m++)
#pragma unroll
    for (int n = 0; n < 4; n++)
#pragma unroll
      for (int r = 0; r < 4; r++) {
        int row = bm * 128 + rowbase + m * 16 + lhi * 4 + r;
        int col = bn * 128 + colbase + n * 16 + llo;
        float v = acc[m][n][r] + bias[col];
        Cout[(size_t)row * N + col] = f2bf(gelu_fast(v));
      }
}

// ---------------- GEMM + residual + LayerNorm fused, split-K-2 ---------------
template <int BASE16, int OUT32>
__global__ __launch_bounds__(512) void k_gemmln(const unsigned short* __restrict__ A,
                                                const unsigned short* __restrict__ Bt,
                                                const float* __restrict__ bias,
                                                const void* __restrict__ base,
                                                const float* __restrict__ alpha,
                                                const float* __restrict__ g,
                                                const float* __restrict__ be,
                                                void* __restrict__ y, int K) {
  __shared__ unsigned short Al[2][32][40];
  __shared__ unsigned short Bl[2][256][40];
  __shared__ float psum[32][4], psq[32][4];
  float* partial = (float*)&Bl[0][0][0];

  const int tid = threadIdx.x;
  const int w = tid >> 6, lane = tid & 63;
  const int kh = w >> 2, wc = w & 3;
  const int lhi = lane >> 4, llo = lane & 15;
  const int row0 = blockIdx.x * 32;
  const int Kh = K >> 1;

  f32x4 zero = {0.f, 0.f, 0.f, 0.f};
  f32x4 acc[2][4];
#pragma unroll
  for (int m = 0; m < 2; m++)
#pragma unroll
    for (int n = 0; n < 4; n++) acc[m][n] = zero;

  for (int kb = 0; kb < Kh; kb += 32) {
    __syncthreads();
    if (tid < 256) {
      int kh2 = tid >> 7, ra = (tid >> 2) & 31, ca = (tid & 3) * 8;
      *(short8*)&Al[kh2][ra][ca] =
          *(const short8*)(A + (size_t)(row0 + ra) * K + kh2 * Kh + kb + ca);
    }
#pragma unroll
    for (int s = 0; s < 4; s++) {
      int c = tid + s * 512;
      int kh2 = c >> 10, rb = (c >> 2) & 255, cb = (c & 3) * 8;
      *(short8*)&Bl[kh2][rb][cb] =
          *(const short8*)(Bt + (size_t)rb * K + kh2 * Kh + kb + cb);
    }
    __syncthreads();
    short8 af[2], bf[4];
#pragma unroll
    for (int m = 0; m < 2; m++) af[m] = *(const short8*)&Al[kh][m * 16 + llo][lhi * 8];
#pragma unroll
    for (int n = 0; n < 4; n++)
      bf[n] = *(const short8*)&Bl[kh][wc * 64 + n * 16 + llo][lhi * 8];
#pragma unroll
    for (int m = 0; m < 2; m++)
#pragma unroll
      for (int n = 0; n < 4; n++)
        acc[m][n] = __builtin_amdgcn_mfma_f32_16x16x32_bf16(af[m], bf[n], acc[m][n], 0, 0, 0);
  }

  __syncthreads();
  if (kh == 1) {
#pragma unroll
    for (int m = 0; m < 2; m++)
#pragma unroll
      for (int n = 0; n < 4; n++)
#pragma unroll
        for (int r = 0; r < 4; r++) {
          int lrow = m * 16 + lhi * 4 + r;
          int col = wc * 64 + n * 16 + llo;
          partial[lrow * 256 + col] = acc[m][n][r];
        }
  }
  __syncthreads();

  const float a = alpha[0];
  const unsigned short* b16 = (const unsigned short*)base;
  const float* b32 = (const float*)base;

  if (kh == 0) {
#pragma unroll
    for (int m = 0; m < 2; m++)
#pragma unroll
      for (int r = 0; r < 4; r++) {
        int lrow = m * 16 + lhi * 4 + r;
        size_t grow = (size_t)(row0 + lrow);
        float s = 0.f, q = 0.f;
#pragma unroll
        for (int n = 0; n < 4; n++) {
          int col = wc * 64 + n * 16 + llo;
          float v = acc[m][n][r] + partial[lrow * 256 + col] + bias[col];
          float xb = BASE16 ? bf2f(b16[grow * 256 + col]) : b32[grow * 256 + col];
          float rr = fmaf(a, v, xb);
          acc[m][n][r] = rr;
          s += rr;
          q = fmaf(rr, rr, q);
        }
#pragma unroll
        for (int off = 1; off < 16; off <<= 1) {
          s += __shfl_xor(s, off);
          q += __shfl_xor(q, off);
        }
        if (llo == 0) { psum[lrow][wc] = s; psq[lrow][wc] = q; }
      }
  }
  __syncthreads();

  if (kh == 0) {
#pragma unroll
    for (int m = 0; m < 2; m++)
#pragma unroll
      for (int r = 0; r < 4; r++) {
        int lrow = m * 16 + lhi * 4 + r;
        size_t grow = (size_t)(row0 + lrow);
        float S = psum[lrow][0] + psum[lrow][1] + psum[lrow][2] + psum[lrow][3];
        float Q = psq[lrow][0] + psq[lrow][1] + psq[lrow][2] + psq[lrow][3];
        float mu = S * (1.0f / 256.0f);
        float var = Q * (1.0f / 256.0f) - mu * mu;
        float rs = rsqrtf(var + 1e-5f);
#pragma unroll
        for (int n = 0; n < 4; n++) {
          int col = wc * 64 + n * 16 + llo;
          float o = (acc[m][n][r] - mu) * rs * g[col] + be[col];
          if (OUT32) ((float*)y)[grow * 256 + col] = o;
          else ((unsigned short*)y)[grow * 256 + col] = f2bf(o);
        }
      }
  }
}

// ---------------- flash attention: 4 waves = 4 key-quarters, 64 q-rows/wave --
// Round-17: r13's 64-q structure with EXPLICIT double-buffered K/V register
// sets (kA/vA <-> kB/vB, loop unrolled x2, all indices static). Prefetch
// writes the *other* buffer, so no VMEM writeback can clobber a register an
// in-flight MFMA reads (r14's suspected failure mode). (256,2): no spill.
__global__ __launch_bounds__(256, 2) void k_attn(const unsigned short* __restrict__ qbuf,
                                                 const unsigned short* __restrict__ kpk,
                                                 const unsigned short* __restrict__ vpk,
                                                 const int* __restrict__ mask,
                                                 unsigned short* __restrict__ ctx) {
  __shared__ float accS[4][64][32];  // 32 KB
  __shared__ float lS[4][64];
  const int tid = threadIdx.x;
  const int lane = tid & 63;
  const int w = tid >> 6;            // key quarter
  const int l31 = lane & 31, hi = lane >> 5;
  const int q0 = blockIdx.x * 64;
  const int h = blockIdx.y, b = blockIdx.z;
  const size_t bS = (size_t)b * S_;

  const unsigned short* QpA = qbuf + (bS + q0 + l31) * 256 + h * DK_ + hi * 8;
  short8 qa0 = *(const short8*)QpA;
  short8 qa1 = *(const short8*)(QpA + 16);
  const unsigned short* QpB = QpA + 32 * 256;
  short8 qb0 = *(const short8*)QpB;
  short8 qb1 = *(const short8*)(QpB + 16);

  const size_t fragbase = ((size_t)(b * H_ + h) * 64 + w * 16) * 2048 + lane * 8;
  const unsigned short* kp = kpk + fragbase;
  const unsigned short* vp = vpk + fragbase;
  const int* mp = mask + bS + w * 1024 + lane;

  f32x16 accA, accB, laccA, laccB;
#pragma unroll
  for (int r = 0; r < 16; r++) { accA[r] = 0.f; accB[r] = 0.f; laccA[r] = 0.f; laccB[r] = 0.f; }
  const f32x16 zz = accA;
  short8 ones;
#pragma unroll
  for (int e = 0; e < 8; e++) ones[e] = (short)0x3F80;

  short8 kA[4], vA[4], kB[4], vB[4];
  unsigned int pk0[8], pk1[8];
  f32x16 s0, s1;
  int tcur = 0;
  int mvC, mvN;

#define LDK(DST) { DST[0] = *(const short8*)(kp); DST[1] = *(const short8*)(kp + 512); \
                   DST[2] = *(const short8*)(kp + 1024); DST[3] = *(const short8*)(kp + 1536); kp += 2048; }
#define LDV(DST) { DST[0] = *(const short8*)(vp); DST[1] = *(const short8*)(vp + 512); \
                   DST[2] = *(const short8*)(vp + 1024); DST[3] = *(const short8*)(vp + 1536); vp += 2048; }
#define QKM(KF, qx0, qx1) {                                                      \
    s0 = __builtin_amdgcn_mfma_f32_32x32x16_bf16(KF[0], qx0, zz, 0, 0, 0);       \
    s1 = __builtin_amdgcn_mfma_f32_32x32x16_bf16(KF[2], qx0, zz, 0, 0, 0);       \
    s0 = __builtin_amdgcn_mfma_f32_32x32x16_bf16(KF[1], qx1, s0, 0, 0, 0);       \
    s1 = __builtin_amdgcn_mfma_f32_32x32x16_bf16(KF[3], qx1, s1, 0, 0, 0);       \
  }
#define EXPM(bal) {                                                              \
    if (__builtin_expect((bal) != ~0ull, 0)) {                                   \
      _Pragma("unroll") for (int r = 0; r < 16; r++) {                           \
        int tt = (r & 3) + 8 * (r >> 2) + 4 * hi;                                \
        if (!(((bal) >> tt) & 1)) s0[r] = -3e38f;                                \
        if (!(((bal) >> (tt + 32)) & 1)) s1[r] = -3e38f;                         \
      }                                                                          \
    }                                                                            \
    _Pragma("unroll") for (int r = 0; r < 16; r++) {                             \
      s0[r] = __builtin_amdgcn_exp2f(s0[r]);                                     \
      s1[r] = __builtin_amdgcn_exp2f(s1[r]);                                     \
    }                                                                            \
    _Pragma("unroll") for (int j = 0; j < 8; j++) {                              \
      asm("v_cvt_pk_bf16_f32 %0, %1, %2" : "=v"(pk0[j]) : "v"(s0[2*j]), "v"(s0[2*j+1])); \
      asm("v_cvt_pk_bf16_f32 %0, %1, %2" : "=v"(pk1[j]) : "v"(s1[2*j]), "v"(s1[2*j+1])); \
    }                                                                            \
  }
#define PVM(VF, accX, laccX) {                                                   \
    __builtin_amdgcn_s_setprio(1);                                               \
    _Pragma("unroll") for (int kk = 0; kk < 4; kk++) {                           \
      unsigned int* pk = (kk < 2) ? pk0 : pk1;                                   \
      int base = (kk & 1) * 4;                                                   \
      auto r02 = __builtin_amdgcn_permlane32_swap(pk[base], pk[base + 2], false, false);     \
      auto r13 = __builtin_amdgcn_permlane32_swap(pk[base + 1], pk[base + 3], false, false); \
      short8 pfr = u32x4_to_s8(r02[0], r13[0], r02[1], r13[1]);                  \
      accX = __builtin_amdgcn_mfma_f32_32x32x16_bf16(pfr, VF[kk], accX, 0, 0, 0);\
      laccX = __builtin_amdgcn_mfma_f32_32x32x16_bf16(pfr, ones, laccX, 0, 0, 0);\
    }                                                                            \
    __builtin_amdgcn_s_setprio(0);                                               \
  }
// One 64-key tile from buffers KC/VC; prefetch next tile into KN/VN.
#define TILESTEP(KC, VC, KN, VN) {                                               \
    unsigned long long bal = __ballot(mvC != 0);                                 \
    QKM(KC, qa0, qa1);                                                           \
    LDK(KN);                                                                     \
    EXPM(bal);                                                                   \
    PVM(VC, accA, laccA);                                                        \
    QKM(KC, qb0, qb1);                                                           \
    LDV(VN);                                                                     \
    EXPM(bal);                                                                   \
    PVM(VC, accB, laccB);                                                        \
    mvC = mvN;                                                                   \
    tcur++;                                                                      \
    mvN = mp[(tcur + 1 < 16 ? tcur + 1 : 15) * 64];                              \
  }

  LDK(kA);   // K(0)
  LDV(vA);   // V(0)
  mvC = mp[0];
  mvN = mp[64];

  for (int it = 0; it < 8; ++it) {
    TILESTEP(kA, vA, kB, vB);   // tiles 0,2,..  prefetch odd tile into B
    TILESTEP(kB, vB, kA, vA);   // tiles 1,3,..  prefetch even tile into A
  }
  // final prefetches over-read one tile (4 KB) into the 1 MB slack; unused.

  // 4-way merge across key-quarters (plain sums; no-max softmax)
#pragma unroll
  for (int r = 0; r < 16; r++) {
    int q = (r & 3) + 8 * (r >> 2) + 4 * hi;
    accS[w][q][l31] = accA[r];
    accS[w][q + 32][l31] = accB[r];
  }
  if (l31 == 0) {
#pragma unroll
    for (int r = 0; r < 16; r++) {
      int q = (r & 3) + 8 * (r >> 2) + 4 * hi;
      lS[w][q] = laccA[r];
      lS[w][q + 32] = laccB[r];
    }
  }
  __syncthreads();
#pragma unroll
  for (int i = 0; i < 8; i++) {
    int e = tid + 256 * i;
    int q = e >> 5, d = e & 31;
    float o = accS[0][q][d] + accS[1][q][d] + accS[2][q][d] + accS[3][q][d];
    float L = lS[0][q] + lS[1][q] + lS[2][q] + lS[3][q];
    ctx[(bS + q0 + q) * (size_t)D_ + h * DK_ + d] = f2bf(o / L);
  }
#undef LDK
#undef LDV
#undef QKM
#undef EXPM
#undef PVM
#undef TILESTEP
}

extern "C" void kernel_launch(void* const* d_in, const int* in_sizes, int n_in,
                              void* d_out, int out_size, void* d_ws, size_t ws_size,
                              hipStream_t stream) {
  const float* x   = (const float*)d_in[0];
  const int* mask  = (const int*)d_in[1];
  const float* Wq  = (const float*)d_in[2];
  const float* bq  = (const float*)d_in[3];
  const float* Wk  = (const float*)d_in[4];
  const float* bk  = (const float*)d_in[5];
  const float* Wv  = (const float*)d_in[6];
  const float* bv  = (const float*)d_in[7];
  const float* Wo  = (const float*)d_in[8];
  const float* bo  = (const float*)d_in[9];
  const float* W1  = (const float*)d_in[10];
  const float* b1  = (const float*)d_in[11];
  const float* W2  = (const float*)d_in[12];
  const float* b2  = (const float*)d_in[13];
  const float* g1  = (const float*)d_in[14];
  const float* be1 = (const float*)d_in[15];
  const float* g2  = (const float*)d_in[16];
  const float* be2 = (const float*)d_in[17];
  const float* a1  = (const float*)d_in[18];
  const float* a2  = (const float*)d_in[19];
  float* out = (float*)d_out;

  char* ws = (char*)d_ws;
  const size_t MB = 1024 * 1024;
  unsigned short* qb  = (unsigned short*)(ws + 0);        // 4 MB
  unsigned short* kpk = (unsigned short*)(ws + 5 * MB);   // 4 MB (+1 MB slack)
  unsigned short* vpk = (unsigned short*)(ws + 10 * MB);  // 4 MB (+1 MB slack)
  unsigned short* ctx = (unsigned short*)(ws + 15 * MB);  // 4 MB
  unsigned short* x1b = (unsigned short*)(ws + 19 * MB);  // 4 MB
  unsigned short* hb  = (unsigned short*)(ws + 23 * MB);  // 16 MB
  unsigned short* WqkvT = (unsigned short*)(ws + 40 * MB);               // 384 KB
  unsigned short* WoT   = (unsigned short*)(ws + 40 * MB + 512 * 1024);  // 128 KB
  unsigned short* W1T   = (unsigned short*)(ws + 41 * MB);               // 512 KB
  unsigned short* W2T   = (unsigned short*)(ws + 41 * MB + 512 * 1024);  // 512 KB
  float* bqkv           = (float*)(ws + 42 * MB);                        // 3 KB
  unsigned short* xb    = (unsigned short*)(ws + 43 * MB);               // 4 MB

  const int NTOK = B_ * S_;  // 8192

  k_prepw<<<dim3(1217), 256, 0, stream>>>(Wq, Wk, Wv, Wo, W1, W2, bq, bk, bv, x,
                                          WqkvT, WoT, W1T, W2T, bqkv, xb);

  k_gemmqkv<<<dim3(64, 6), 256, 0, stream>>>(xb, WqkvT, bqkv, qb, kpk, vpk);

  k_attn<<<dim3(S_ / 64, H_, B_), 256, 0, stream>>>(qb, kpk, vpk, mask, ctx);

  // Wo GEMM + residual(x) + LN1 -> x1b (bf16)
  k_gemmln<0, 0><<<dim3(NTOK / 32), 512, 0, stream>>>(ctx, WoT, bo, x, a1, g1, be1,
                                                      x1b, 256);

  k_gemm1<<<dim3(64, 8), 256, 0, stream>>>(x1b, W1T, b1, hb, NTOK, 1024, 256);

  // W2 GEMM + residual(x1b) + LN2 -> out (f32)
  k_gemmln<1, 1><<<dim3(NTOK / 32), 512, 0, stream>>>(hb, W2T, b2, x1b, a2, g2, be2,
                                                      out, 1024);
}

// Round 18
// 112.483 us; speedup vs baseline: 1.1645x; 1.0964x over previous
//
#include <hip/hip_runtime.h>
#include <hip/hip_bf16.h>
#include <math.h>

#define B_ 2
#define S_ 4096
#define D_ 256
#define H_ 8
#define DFF_ 1024
#define DK_ 32

typedef __attribute__((ext_vector_type(8))) short short8;
typedef __attribute__((ext_vector_type(4))) float f32x4;
typedef __attribute__((ext_vector_type(16))) float f32x16;
typedef __attribute__((ext_vector_type(4))) int int4v;

__device__ __forceinline__ unsigned short f2bf(float f) {
  unsigned int u = __builtin_bit_cast(unsigned int, f);
  u += 0x7FFFu + ((u >> 16) & 1u);
  return (unsigned short)(u >> 16);
}

__device__ __forceinline__ float bf2f(unsigned short s) {
  unsigned int u = ((unsigned int)s) << 16;
  return __builtin_bit_cast(float, u);
}

__device__ __forceinline__ short8 u32x4_to_s8(unsigned int a, unsigned int b,
                                              unsigned int c, unsigned int d) {
  int4v v = {(int)a, (int)b, (int)c, (int)d};
  return __builtin_bit_cast(short8, v);
}

// fast GELU (tanh form), NaN-safe at extremes; |err| vs exact erf-GELU < ~1e-3
__device__ __forceinline__ float gelu_fast(float v) {
  float e = __builtin_amdgcn_exp2f(v * fmaf(0.10294609f, v * v, 2.3022077f));
  float th = 1.0f - 2.0f * __builtin_amdgcn_rcpf(e + 1.0f);
  return 0.5f * v * (1.0f + th);
}

// ---------------- fused prep ---------------------------------------------------
// Wq/Wk/Wv -> WqkvT row-major [768][256] (+k2 on Wq); Wo -> WoT row-major.
// W1 -> W1pk, W2 -> W2pk in MFMA B-fragment chunk order:
//   chunk(ntile, kstep): 64 lanes x 16B; value e = W[k=kstep*32+(lane>>4)*8+e][n=ntile*16+(lane&15)]
// bias concat; x -> bf16.
__global__ __launch_bounds__(256) void k_prepw(
    const float* __restrict__ Wq, const float* __restrict__ Wk,
    const float* __restrict__ Wv, const float* __restrict__ Wo,
    const float* __restrict__ W1, const float* __restrict__ W2,
    const float* __restrict__ bq, const float* __restrict__ bk,
    const float* __restrict__ bv, const float* __restrict__ x,
    unsigned short* __restrict__ WqkvT, unsigned short* __restrict__ WoT,
    unsigned short* __restrict__ W1pk, unsigned short* __restrict__ W2pk,
    float* __restrict__ bqkv, unsigned short* __restrict__ xb) {
  const float k2 = 0.25500525551f;  // log2(e)/sqrt(DK)
  int bx = blockIdx.x, t = threadIdx.x;

  if (bx < 192) {
    __shared__ float tile[64][65];
    const float* src;
    int Nsz, ti, tj;
    float scale = 1.0f;
    if (bx < 48) {
      int which = bx >> 4, s = bx & 15;
      src = (which == 0) ? Wq : (which == 1) ? Wk : Wv;
      Nsz = 256; ti = s >> 2; tj = s & 3;
      if (which == 0) scale = k2;
    } else if (bx < 64) {
      int s = bx - 48;
      src = Wo; Nsz = 256; ti = s >> 2; tj = s & 3;
    } else if (bx < 128) {
      int s = bx - 64;
      src = W1; Nsz = 1024; ti = s >> 4; tj = s & 15;
    } else {
      int s = bx - 128;
      src = W2; Nsz = 256; ti = s >> 2; tj = s & 3;
    }
    int row0 = ti * 64, col0 = tj * 64;
    int c = t & 63, rg = t >> 6;
#pragma unroll
    for (int i = 0; i < 16; i++) {
      int rr = rg * 16 + i;
      tile[rr][c] = src[(size_t)(row0 + rr) * Nsz + col0 + c] * scale;
    }
    __syncthreads();

    if (bx < 64) {
      // row-major transposed output (WqkvT / WoT)
      unsigned short* dst;
      if (bx < 48) dst = WqkvT + (bx >> 4) * 65536;
      else dst = WoT;
      int k = t & 63;
#pragma unroll
      for (int i = 0; i < 16; i++) {
        int nn = rg * 16 + i;
        dst[(size_t)(col0 + nn) * 256 + row0 + k] = f2bf(tile[k][nn]);
      }
    } else {
      // fragment-packed output (W1pk / W2pk)
      unsigned short* pk = (bx < 128) ? W1pk : W2pk;
      int kst_tot = (bx < 128) ? 8 : 32;
      int lane2 = t & 63, sub2 = t >> 6;
#pragma unroll
      for (int i = 0; i < 2; i++) {
        int subc = sub2 * 2 + i;          // 0..7
        int ntl = subc >> 1, kst = subc & 1;
        short8 o;
#pragma unroll
        for (int e = 0; e < 8; e++)
          o[e] = (short)f2bf(tile[kst * 32 + (lane2 >> 4) * 8 + e][ntl * 16 + (lane2 & 15)]);
        int ntg = tj * 4 + ntl;
        int ksg = ti * 2 + kst;
        *(short8*)(pk + ((size_t)(ntg * kst_tot + ksg) * 64 + lane2) * 8) = o;
      }
    }
  } else if (bx == 192) {
#pragma unroll
    for (int j = 0; j < 3; j++) {
      int i = j * 256 + t;
      if (i < 768)
        bqkv[i] = (i < 256) ? bq[i] * k2 : (i < 512) ? bk[i - 256] : bv[i - 512];
    }
  } else {
    int i = (bx - 193) * 2048 + t * 8;
    f32x4 f0 = *(const f32x4*)(x + i);
    f32x4 f1 = *(const f32x4*)(x + i + 4);
    short8 o;
#pragma unroll
    for (int e = 0; e < 4; e++) { o[e] = (short)f2bf(f0[e]); o[e + 4] = (short)f2bf(f1[e]); }
    *(short8*)(xb + i) = o;
  }
}

// ---------------- QKV GEMM (BN=128) with fragment-scatter epilogue -----------
__global__ __launch_bounds__(256) void k_gemmqkv(const unsigned short* __restrict__ A,
                                                 const unsigned short* __restrict__ Bt,
                                                 const float* __restrict__ bias,
                                                 unsigned short* __restrict__ qb,
                                                 unsigned short* __restrict__ kpk,
                                                 unsigned short* __restrict__ vpk) {
  const int K = 256;
  __shared__ unsigned short Al[128][40];
  __shared__ unsigned short Bl[128][40];
  const int tid = threadIdx.x;
  const int wid = tid >> 6, lane = tid & 63;
  const int lhi = lane >> 4, llo = lane & 15;
  const int wr = wid >> 1, wc = wid & 1;
  const int rowbase = wr * 64, colbase = wc * 64;
  const int bm = blockIdx.x, bn = blockIdx.y;

  f32x4 zero = {0.f, 0.f, 0.f, 0.f};
  f32x4 acc[4][4];
#pragma unroll
  for (int m = 0; m < 4; m++)
#pragma unroll
    for (int n = 0; n < 4; n++) acc[m][n] = zero;

  const int r0 = tid >> 2, c8 = (tid & 3) * 8;
  const unsigned short* A16a = A + (size_t)(bm * 128 + r0) * K + c8;
  const unsigned short* A16b = A + (size_t)(bm * 128 + r0 + 64) * K + c8;
  const unsigned short* Brow0 = Bt + (size_t)(bn * 128 + r0) * K + c8;
  const unsigned short* Brow1 = Bt + (size_t)(bn * 128 + r0 + 64) * K + c8;

  for (int kb = 0; kb < K; kb += 32) {
    __syncthreads();
    *(short8*)&Al[r0][c8] = *(const short8*)(A16a + kb);
    *(short8*)&Al[r0 + 64][c8] = *(const short8*)(A16b + kb);
    *(short8*)&Bl[r0][c8] = *(const short8*)(Brow0 + kb);
    *(short8*)&Bl[r0 + 64][c8] = *(const short8*)(Brow1 + kb);
    __syncthreads();
    short8 af[4], bf[4];
#pragma unroll
    for (int m = 0; m < 4; m++) af[m] = *(const short8*)&Al[rowbase + m * 16 + llo][lhi * 8];
#pragma unroll
    for (int n = 0; n < 4; n++) bf[n] = *(const short8*)&Bl[colbase + n * 16 + llo][lhi * 8];
#pragma unroll
    for (int m = 0; m < 4; m++)
#pragma unroll
      for (int n = 0; n < 4; n++)
        acc[m][n] = __builtin_amdgcn_mfma_f32_16x16x32_bf16(af[m], bf[n], acc[m][n], 0, 0, 0);
  }

#pragma unroll
  for (int m = 0; m < 4; m++)
#pragma unroll
    for (int n = 0; n < 4; n++)
#pragma unroll
      for (int r = 0; r < 4; r++) {
        int row = bm * 128 + rowbase + m * 16 + lhi * 4 + r;
        int gcol = bn * 128 + colbase + n * 16 + llo;
        int which = gcol >> 8;  // 0=Q, 1=K, 2=V
        int col0 = gcol & 255;
        float v = acc[m][n][r] + bias[gcol];
        unsigned short bv = f2bf(v);
        int t = row & (S_ - 1), b = row >> 12;
        int h = col0 >> 5;
        if (which == 0) {
          qb[(size_t)row * 256 + col0] = bv;
        } else if (which == 1) {
          int c5 = col0 & 31, jj = (c5 >> 4) & 1, hik = (c5 >> 3) & 1, e = c5 & 7;
          int tile = t >> 6, i = (t >> 5) & 1, l31k = t & 31;
          size_t addr = (((size_t)(b * 8 + h) * 64 + tile) * 4 + i * 2 + jj) * 512 +
                        (hik * 32 + l31k) * 8 + e;
          kpk[addr] = bv;
        } else {
          int d = col0 & 31;
          int x5 = t >> 6, j = (t >> 3) & 7, kk = t & 7;
          size_t addr = (((size_t)(b * 8 + h) * 64 + x5) * 4 + (j >> 1)) * 512 +
                        ((j & 1) * 32 + d) * 8 + kk;
          vpk[addr] = bv;
        }
      }
}

// ---------------- fused FFN: out = LN(x1b + a2*(GELU(x1b@W1+b1)@W2+b2)) ------
// 256 blocks x 512 thr (8 waves). 32 rows/block; 4 dff-chunks of 256.
// W1pk/W2pk are fragment-packed; B-frags read directly from global (L2-fit).
__global__ __launch_bounds__(512) void k_ffn(const unsigned short* __restrict__ x1b,
                                             const unsigned short* __restrict__ W1pk,
                                             const float* __restrict__ b1,
                                             const unsigned short* __restrict__ W2pk,
                                             const float* __restrict__ b2,
                                             const float* __restrict__ alpha,
                                             const float* __restrict__ g,
                                             const float* __restrict__ be,
                                             float* __restrict__ out) {
  __shared__ unsigned short Ax[32][268];  // x1b rows (also residual base)
  __shared__ unsigned short Hl[32][268];  // GELU output chunk (256 dff)
  __shared__ float psum[32][8], psq[32][8];
  const int tid = threadIdx.x;
  const int w = tid >> 6, lane = tid & 63;
  const int lhi = lane >> 4, llo = lane & 15;
  const int row0 = blockIdx.x * 32;

  {
    int r = tid >> 4, c0 = (tid & 15) * 16;
    const unsigned short* src = x1b + (size_t)(row0 + r) * 256 + c0;
    *(short8*)&Ax[r][c0] = *(const short8*)(src);
    *(short8*)&Ax[r][c0 + 8] = *(const short8*)(src + 8);
  }
  __syncthreads();

  f32x4 zero4 = {0.f, 0.f, 0.f, 0.f};
  f32x4 acc2[2][2];
#pragma unroll
  for (int m = 0; m < 2; m++)
#pragma unroll
    for (int n = 0; n < 2; n++) acc2[m][n] = zero4;

  for (int c = 0; c < 4; ++c) {
    // ---- GEMM1: h[32 x 256] (this wave: cols w*32..w*32+31), K = 256
    f32x4 acc1[2][2];
#pragma unroll
    for (int m = 0; m < 2; m++)
#pragma unroll
      for (int n = 0; n < 2; n++) acc1[m][n] = zero4;
    const unsigned short* w1base = W1pk + (size_t)(c * 16 + w * 2) * 4096 + lane * 8;
#pragma unroll
    for (int kb = 0; kb < 8; ++kb) {
      short8 af0 = *(const short8*)&Ax[llo][kb * 32 + lhi * 8];
      short8 af1 = *(const short8*)&Ax[16 + llo][kb * 32 + lhi * 8];
      short8 bf0 = *(const short8*)(w1base + kb * 512);
      short8 bf1 = *(const short8*)(w1base + 4096 + kb * 512);
      acc1[0][0] = __builtin_amdgcn_mfma_f32_16x16x32_bf16(af0, bf0, acc1[0][0], 0, 0, 0);
      acc1[0][1] = __builtin_amdgcn_mfma_f32_16x16x32_bf16(af0, bf1, acc1[0][1], 0, 0, 0);
      acc1[1][0] = __builtin_amdgcn_mfma_f32_16x16x32_bf16(af1, bf0, acc1[1][0], 0, 0, 0);
      acc1[1][1] = __builtin_amdgcn_mfma_f32_16x16x32_bf16(af1, bf1, acc1[1][1], 0, 0, 0);
    }
    __syncthreads();  // S1: all waves finished reading Hl (prev chunk GEMM2)
#pragma unroll
    for (int m = 0; m < 2; m++)
#pragma unroll
      for (int n = 0; n < 2; n++)
#pragma unroll
        for (int r = 0; r < 4; r++) {
          int col = w * 32 + n * 16 + llo;
          float v = acc1[m][n][r] + b1[c * 256 + col];
          Hl[m * 16 + lhi * 4 + r][col] = f2bf(gelu_fast(v));
        }
    __syncthreads();  // S2: Hl visible
    // ---- GEMM2: acc2 += Hl[32 x 256] @ W2 cols (this wave: cols w*32..w*32+31)
    const unsigned short* w2base = W2pk + (size_t)(w * 2) * 16384 + (size_t)(c * 8) * 512 + lane * 8;
#pragma unroll
    for (int kk = 0; kk < 8; ++kk) {
      short8 a0 = *(const short8*)&Hl[llo][kk * 32 + lhi * 8];
      short8 a1 = *(const short8*)&Hl[16 + llo][kk * 32 + lhi * 8];
      short8 bf0 = *(const short8*)(w2base + kk * 512);
      short8 bf1 = *(const short8*)(w2base + 16384 + kk * 512);
      acc2[0][0] = __builtin_amdgcn_mfma_f32_16x16x32_bf16(a0, bf0, acc2[0][0], 0, 0, 0);
      acc2[0][1] = __builtin_amdgcn_mfma_f32_16x16x32_bf16(a0, bf1, acc2[0][1], 0, 0, 0);
      acc2[1][0] = __builtin_amdgcn_mfma_f32_16x16x32_bf16(a1, bf0, acc2[1][0], 0, 0, 0);
      acc2[1][1] = __builtin_amdgcn_mfma_f32_16x16x32_bf16(a1, bf1, acc2[1][1], 0, 0, 0);
    }
    // next chunk's S1 protects Hl before overwrite
  }

  // ---- epilogue: residual(x1b from Ax) + LayerNorm -> out (f32)
  const float a = alpha[0];
#pragma unroll
  for (int m = 0; m < 2; m++)
#pragma unroll
    for (int r = 0; r < 4; r++) {
      int lrow = m * 16 + lhi * 4 + r;
      float s = 0.f, q = 0.f;
#pragma unroll
      for (int n = 0; n < 2; n++) {
        int col = w * 32 + n * 16 + llo;
        float v = acc2[m][n][r] + b2[col];
        float xv = bf2f(Ax[lrow][col]);
        float rr = fmaf(a, v, xv);
        acc2[m][n][r] = rr;
        s += rr;
        q = fmaf(rr, rr, q);
      }
#pragma unroll
      for (int off = 1; off < 16; off <<= 1) {
        s += __shfl_xor(s, off);
        q += __shfl_xor(q, off);
      }
      if (llo == 0) { psum[lrow][w] = s; psq[lrow][w] = q; }
    }
  __syncthreads();
#pragma unroll
  for (int m = 0; m < 2; m++)
#pragma unroll
    for (int r = 0; r < 4; r++) {
      int lrow = m * 16 + lhi * 4 + r;
      size_t grow = (size_t)(row0 + lrow);
      float S = 0.f, Q = 0.f;
#pragma unroll
      for (int j = 0; j < 8; j++) { S += psum[lrow][j]; Q += psq[lrow][j]; }
      float mu = S * (1.0f / 256.0f);
      float var = Q * (1.0f / 256.0f) - mu * mu;
      float rs = rsqrtf(var + 1e-5f);
#pragma unroll
      for (int n = 0; n < 2; n++) {
        int col = w * 32 + n * 16 + llo;
        out[grow * 256 + col] = (acc2[m][n][r] - mu) * rs * g[col] + be[col];
      }
    }
}

// ---------------- GEMM + residual + LayerNorm fused, split-K-2 (Wo path) -----
template <int BASE16, int OUT32>
__global__ __launch_bounds__(512) void k_gemmln(const unsigned short* __restrict__ A,
                                                const unsigned short* __restrict__ Bt,
                                                const float* __restrict__ bias,
                                                const void* __restrict__ base,
                                                const float* __restrict__ alpha,
                                                const float* __restrict__ g,
                                                const float* __restrict__ be,
                                                void* __restrict__ y, int K) {
  __shared__ unsigned short Al[2][32][40];
  __shared__ unsigned short Bl[2][256][40];
  __shared__ float psum[32][4], psq[32][4];
  float* partial = (float*)&Bl[0][0][0];

  const int tid = threadIdx.x;
  const int w = tid >> 6, lane = tid & 63;
  const int kh = w >> 2, wc = w & 3;
  const int lhi = lane >> 4, llo = lane & 15;
  const int row0 = blockIdx.x * 32;
  const int Kh = K >> 1;

  f32x4 zero = {0.f, 0.f, 0.f, 0.f};
  f32x4 acc[2][4];
#pragma unroll
  for (int m = 0; m < 2; m++)
#pragma unroll
    for (int n = 0; n < 4; n++) acc[m][n] = zero;

  for (int kb = 0; kb < Kh; kb += 32) {
    __syncthreads();
    if (tid < 256) {
      int kh2 = tid >> 7, ra = (tid >> 2) & 31, ca = (tid & 3) * 8;
      *(short8*)&Al[kh2][ra][ca] =
          *(const short8*)(A + (size_t)(row0 + ra) * K + kh2 * Kh + kb + ca);
    }
#pragma unroll
    for (int s = 0; s < 4; s++) {
      int c = tid + s * 512;
      int kh2 = c >> 10, rb = (c >> 2) & 255, cb = (c & 3) * 8;
      *(short8*)&Bl[kh2][rb][cb] =
          *(const short8*)(Bt + (size_t)rb * K + kh2 * Kh + kb + cb);
    }
    __syncthreads();
    short8 af[2], bf[4];
#pragma unroll
    for (int m = 0; m < 2; m++) af[m] = *(const short8*)&Al[kh][m * 16 + llo][lhi * 8];
#pragma unroll
    for (int n = 0; n < 4; n++)
      bf[n] = *(const short8*)&Bl[kh][wc * 64 + n * 16 + llo][lhi * 8];
#pragma unroll
    for (int m = 0; m < 2; m++)
#pragma unroll
      for (int n = 0; n < 4; n++)
        acc[m][n] = __builtin_amdgcn_mfma_f32_16x16x32_bf16(af[m], bf[n], acc[m][n], 0, 0, 0);
  }

  __syncthreads();
  if (kh == 1) {
#pragma unroll
    for (int m = 0; m < 2; m++)
#pragma unroll
      for (int n = 0; n < 4; n++)
#pragma unroll
        for (int r = 0; r < 4; r++) {
          int lrow = m * 16 + lhi * 4 + r;
          int col = wc * 64 + n * 16 + llo;
          partial[lrow * 256 + col] = acc[m][n][r];
        }
  }
  __syncthreads();

  const float a = alpha[0];
  const unsigned short* b16 = (const unsigned short*)base;
  const float* b32 = (const float*)base;

  if (kh == 0) {
#pragma unroll
    for (int m = 0; m < 2; m++)
#pragma unroll
      for (int r = 0; r < 4; r++) {
        int lrow = m * 16 + lhi * 4 + r;
        size_t grow = (size_t)(row0 + lrow);
        float s = 0.f, q = 0.f;
#pragma unroll
        for (int n = 0; n < 4; n++) {
          int col = wc * 64 + n * 16 + llo;
          float v = acc[m][n][r] + partial[lrow * 256 + col] + bias[col];
          float xb = BASE16 ? bf2f(b16[grow * 256 + col]) : b32[grow * 256 + col];
          float rr = fmaf(a, v, xb);
          acc[m][n][r] = rr;
          s += rr;
          q = fmaf(rr, rr, q);
        }
#pragma unroll
        for (int off = 1; off < 16; off <<= 1) {
          s += __shfl_xor(s, off);
          q += __shfl_xor(q, off);
        }
        if (llo == 0) { psum[lrow][wc] = s; psq[lrow][wc] = q; }
      }
  }
  __syncthreads();

  if (kh == 0) {
#pragma unroll
    for (int m = 0; m < 2; m++)
#pragma unroll
      for (int r = 0; r < 4; r++) {
        int lrow = m * 16 + lhi * 4 + r;
        size_t grow = (size_t)(row0 + lrow);
        float S = psum[lrow][0] + psum[lrow][1] + psum[lrow][2] + psum[lrow][3];
        float Q = psq[lrow][0] + psq[lrow][1] + psq[lrow][2] + psq[lrow][3];
        float mu = S * (1.0f / 256.0f);
        float var = Q * (1.0f / 256.0f) - mu * mu;
        float rs = rsqrtf(var + 1e-5f);
#pragma unroll
        for (int n = 0; n < 4; n++) {
          int col = wc * 64 + n * 16 + llo;
          float o = (acc[m][n][r] - mu) * rs * g[col] + be[col];
          if (OUT32) ((float*)y)[grow * 256 + col] = o;
          else ((unsigned short*)y)[grow * 256 + col] = f2bf(o);
        }
      }
  }
}

// ---------------- flash attention: 4 waves = 4 key-quarters, 64 q-rows/wave --
// (round-17 version: explicit double-buffered K/V registers, verified stable)
__global__ __launch_bounds__(256, 2) void k_attn(const unsigned short* __restrict__ qbuf,
                                                 const unsigned short* __restrict__ kpk,
                                                 const unsigned short* __restrict__ vpk,
                                                 const int* __restrict__ mask,
                                                 unsigned short* __restrict__ ctx) {
  __shared__ float accS[4][64][32];  // 32 KB
  __shared__ float lS[4][64];
  const int tid = threadIdx.x;
  const int lane = tid & 63;
  const int w = tid >> 6;            // key quarter
  const int l31 = lane & 31, hi = lane >> 5;
  const int q0 = blockIdx.x * 64;
  const int h = blockIdx.y, b = blockIdx.z;
  const size_t bS = (size_t)b * S_;

  const unsigned short* QpA = qbuf + (bS + q0 + l31) * 256 + h * DK_ + hi * 8;
  short8 qa0 = *(const short8*)QpA;
  short8 qa1 = *(const short8*)(QpA + 16);
  const unsigned short* QpB = QpA + 32 * 256;
  short8 qb0 = *(const short8*)QpB;
  short8 qb1 = *(const short8*)(QpB + 16);

  const size_t fragbase = ((size_t)(b * H_ + h) * 64 + w * 16) * 2048 + lane * 8;
  const unsigned short* kp = kpk + fragbase;
  const unsigned short* vp = vpk + fragbase;
  const int* mp = mask + bS + w * 1024 + lane;

  f32x16 accA, accB, laccA, laccB;
#pragma unroll
  for (int r = 0; r < 16; r++) { accA[r] = 0.f; accB[r] = 0.f; laccA[r] = 0.f; laccB[r] = 0.f; }
  const f32x16 zz = accA;
  short8 ones;
#pragma unroll
  for (int e = 0; e < 8; e++) ones[e] = (short)0x3F80;

  short8 kA[4], vA[4], kB[4], vB[4];
  unsigned int pk0[8], pk1[8];
  f32x16 s0, s1;
  int tcur = 0;
  int mvC, mvN;

#define LDK(DST) { DST[0] = *(const short8*)(kp); DST[1] = *(const short8*)(kp + 512); \
                   DST[2] = *(const short8*)(kp + 1024); DST[3] = *(const short8*)(kp + 1536); kp += 2048; }
#define LDV(DST) { DST[0] = *(const short8*)(vp); DST[1] = *(const short8*)(vp + 512); \
                   DST[2] = *(const short8*)(vp + 1024); DST[3] = *(const short8*)(vp + 1536); vp += 2048; }
#define QKM(KF, qx0, qx1) {                                                      \
    s0 = __builtin_amdgcn_mfma_f32_32x32x16_bf16(KF[0], qx0, zz, 0, 0, 0);       \
    s1 = __builtin_amdgcn_mfma_f32_32x32x16_bf16(KF[2], qx0, zz, 0, 0, 0);       \
    s0 = __builtin_amdgcn_mfma_f32_32x32x16_bf16(KF[1], qx1, s0, 0, 0, 0);       \
    s1 = __builtin_amdgcn_mfma_f32_32x32x16_bf16(KF[3], qx1, s1, 0, 0, 0);       \
  }
#define EXPM(bal) {                                                              \
    if (__builtin_expect((bal) != ~0ull, 0)) {                                   \
      _Pragma("unroll") for (int r = 0; r < 16; r++) {                           \
        int tt = (r & 3) + 8 * (r >> 2) + 4 * hi;                                \
        if (!(((bal) >> tt) & 1)) s0[r] = -3e38f;                                \
        if (!(((bal) >> (tt + 32)) & 1)) s1[r] = -3e38f;                         \
      }                                                                          \
    }                                                                            \
    _Pragma("unroll") for (int r = 0; r < 16; r++) {                             \
      s0[r] = __builtin_amdgcn_exp2f(s0[r]);                                     \
      s1[r] = __builtin_amdgcn_exp2f(s1[r]);                                     \
    }                                                                            \
    _Pragma("unroll") for (int j = 0; j < 8; j++) {                              \
      asm("v_cvt_pk_bf16_f32 %0, %1, %2" : "=v"(pk0[j]) : "v"(s0[2*j]), "v"(s0[2*j+1])); \
      asm("v_cvt_pk_bf16_f32 %0, %1, %2" : "=v"(pk1[j]) : "v"(s1[2*j]), "v"(s1[2*j+1])); \
    }                                                                            \
  }
#define PVM(VF, accX, laccX) {                                                   \
    __builtin_amdgcn_s_setprio(1);                                               \
    _Pragma("unroll") for (int kk = 0; kk < 4; kk++) {                           \
      unsigned int* pk = (kk < 2) ? pk0 : pk1;                                   \
      int base = (kk & 1) * 4;                                                   \
      auto r02 = __builtin_amdgcn_permlane32_swap(pk[base], pk[base + 2], false, false);     \
      auto r13 = __builtin_amdgcn_permlane32_swap(pk[base + 1], pk[base + 3], false, false); \
      short8 pfr = u32x4_to_s8(r02[0], r13[0], r02[1], r13[1]);                  \
      accX = __builtin_amdgcn_mfma_f32_32x32x16_bf16(pfr, VF[kk], accX, 0, 0, 0);\
      laccX = __builtin_amdgcn_mfma_f32_32x32x16_bf16(pfr, ones, laccX, 0, 0, 0);\
    }                                                                            \
    __builtin_amdgcn_s_setprio(0);                                               \
  }
#define TILESTEP(KC, VC, KN, VN) {                                               \
    unsigned long long bal = __ballot(mvC != 0);                                 \
    QKM(KC, qa0, qa1);                                                           \
    LDK(KN);                                                                     \
    EXPM(bal);                                                                   \
    PVM(VC, accA, laccA);                                                        \
    QKM(KC, qb0, qb1);                                                           \
    LDV(VN);                                                                     \
    EXPM(bal);                                                                   \
    PVM(VC, accB, laccB);                                                        \
    mvC = mvN;                                                                   \
    tcur++;                                                                      \
    mvN = mp[(tcur + 1 < 16 ? tcur + 1 : 15) * 64];                              \
  }

  LDK(kA);   // K(0)
  LDV(vA);   // V(0)
  mvC = mp[0];
  mvN = mp[64];

  for (int it = 0; it < 8; ++it) {
    TILESTEP(kA, vA, kB, vB);
    TILESTEP(kB, vB, kA, vA);
  }

  // 4-way merge across key-quarters (plain sums; no-max softmax)
#pragma unroll
  for (int r = 0; r < 16; r++) {
    int q = (r & 3) + 8 * (r >> 2) + 4 * hi;
    accS[w][q][l31] = accA[r];
    accS[w][q + 32][l31] = accB[r];
  }
  if (l31 == 0) {
#pragma unroll
    for (int r = 0; r < 16; r++) {
      int q = (r & 3) + 8 * (r >> 2) + 4 * hi;
      lS[w][q] = laccA[r];
      lS[w][q + 32] = laccB[r];
    }
  }
  __syncthreads();
#pragma unroll
  for (int i = 0; i < 8; i++) {
    int e = tid + 256 * i;
    int q = e >> 5, d = e & 31;
    float o = accS[0][q][d] + accS[1][q][d] + accS[2][q][d] + accS[3][q][d];
    float L = lS[0][q] + lS[1][q] + lS[2][q] + lS[3][q];
    ctx[(bS + q0 + q) * (size_t)D_ + h * DK_ + d] = f2bf(o / L);
  }
#undef LDK
#undef LDV
#undef QKM
#undef EXPM
#undef PVM
#undef TILESTEP
}

extern "C" void kernel_launch(void* const* d_in, const int* in_sizes, int n_in,
                              void* d_out, int out_size, void* d_ws, size_t ws_size,
                              hipStream_t stream) {
  const float* x   = (const float*)d_in[0];
  const int* mask  = (const int*)d_in[1];
  const float* Wq  = (const float*)d_in[2];
  const float* bq  = (const float*)d_in[3];
  const float* Wk  = (const float*)d_in[4];
  const float* bk  = (const float*)d_in[5];
  const float* Wv  = (const float*)d_in[6];
  const float* bv  = (const float*)d_in[7];
  const float* Wo  = (const float*)d_in[8];
  const float* bo  = (const float*)d_in[9];
  const float* W1  = (const float*)d_in[10];
  const float* b1  = (const float*)d_in[11];
  const float* W2  = (const float*)d_in[12];
  const float* b2  = (const float*)d_in[13];
  const float* g1  = (const float*)d_in[14];
  const float* be1 = (const float*)d_in[15];
  const float* g2  = (const float*)d_in[16];
  const float* be2 = (const float*)d_in[17];
  const float* a1  = (const float*)d_in[18];
  const float* a2  = (const float*)d_in[19];
  float* out = (float*)d_out;

  char* ws = (char*)d_ws;
  const size_t MB = 1024 * 1024;
  unsigned short* qb  = (unsigned short*)(ws + 0);        // 4 MB
  unsigned short* kpk = (unsigned short*)(ws + 5 * MB);   // 4 MB (+1 MB slack)
  unsigned short* vpk = (unsigned short*)(ws + 10 * MB);  // 4 MB (+1 MB slack)
  unsigned short* ctx = (unsigned short*)(ws + 15 * MB);  // 4 MB
  unsigned short* x1b = (unsigned short*)(ws + 19 * MB);  // 4 MB
  unsigned short* WqkvT = (unsigned short*)(ws + 40 * MB);               // 384 KB
  unsigned short* WoT   = (unsigned short*)(ws + 40 * MB + 512 * 1024);  // 128 KB
  unsigned short* W1pk  = (unsigned short*)(ws + 41 * MB);               // 512 KB
  unsigned short* W2pk  = (unsigned short*)(ws + 41 * MB + 512 * 1024);  // 512 KB
  float* bqkv           = (float*)(ws + 42 * MB);                        // 3 KB
  unsigned short* xb    = (unsigned short*)(ws + 43 * MB);               // 4 MB

  const int NTOK = B_ * S_;  // 8192

  k_prepw<<<dim3(1217), 256, 0, stream>>>(Wq, Wk, Wv, Wo, W1, W2, bq, bk, bv, x,
                                          WqkvT, WoT, W1pk, W2pk, bqkv, xb);

  k_gemmqkv<<<dim3(64, 6), 256, 0, stream>>>(xb, WqkvT, bqkv, qb, kpk, vpk);

  k_attn<<<dim3(S_ / 64, H_, B_), 256, 0, stream>>>(qb, kpk, vpk, mask, ctx);

  // Wo GEMM + residual(x) + LN1 -> x1b (bf16)
  k_gemmln<0, 0><<<dim3(NTOK / 32), 512, 0, stream>>>(ctx, WoT, bo, x, a1, g1, be1,
                                                      x1b, 256);

  // fused FFN + residual + LN2 -> out (f32)
  k_ffn<<<dim3(NTOK / 32), 512, 0, stream>>>(x1b, W1pk, b1, W2pk, b2, a2, g2, be2, out);
}

// Round 19
// 108.596 us; speedup vs baseline: 1.2062x; 1.0358x over previous
//
#include <hip/hip_runtime.h>
#include <hip/hip_bf16.h>
#include <math.h>

#define B_ 2
#define S_ 4096
#define D_ 256
#define H_ 8
#define DFF_ 1024
#define DK_ 32

typedef __attribute__((ext_vector_type(8))) short short8;
typedef __attribute__((ext_vector_type(4))) float f32x4;
typedef __attribute__((ext_vector_type(16))) float f32x16;
typedef __attribute__((ext_vector_type(4))) int int4v;

__device__ __forceinline__ unsigned short f2bf(float f) {
  unsigned int u = __builtin_bit_cast(unsigned int, f);
  u += 0x7FFFu + ((u >> 16) & 1u);
  return (unsigned short)(u >> 16);
}

__device__ __forceinline__ float bf2f(unsigned short s) {
  unsigned int u = ((unsigned int)s) << 16;
  return __builtin_bit_cast(float, u);
}

__device__ __forceinline__ short8 u32x4_to_s8(unsigned int a, unsigned int b,
                                              unsigned int c, unsigned int d) {
  int4v v = {(int)a, (int)b, (int)c, (int)d};
  return __builtin_bit_cast(short8, v);
}

// fast GELU (tanh form), NaN-safe at extremes; |err| vs exact erf-GELU < ~1e-3
__device__ __forceinline__ float gelu_fast(float v) {
  float e = __builtin_amdgcn_exp2f(v * fmaf(0.10294609f, v * v, 2.3022077f));
  float th = 1.0f - 2.0f * __builtin_amdgcn_rcpf(e + 1.0f);
  return 0.5f * v * (1.0f + th);
}

// ---------------- fused prep ---------------------------------------------------
// Wq/Wk/Wv -> WqkvT row-major [768][256] (+k2 on Wq).
// Wo -> Wopk, W1 -> W1pk, W2 -> W2pk in MFMA B-fragment chunk order:
//   chunk(ntile, kstep): 64 lanes x 16B; elem e = W[kstep*32+(lane>>4)*8+e][ntile*16+(lane&15)]
__global__ __launch_bounds__(256) void k_prepw(
    const float* __restrict__ Wq, const float* __restrict__ Wk,
    const float* __restrict__ Wv, const float* __restrict__ Wo,
    const float* __restrict__ W1, const float* __restrict__ W2,
    const float* __restrict__ bq, const float* __restrict__ bk,
    const float* __restrict__ bv, const float* __restrict__ x,
    unsigned short* __restrict__ WqkvT, unsigned short* __restrict__ Wopk,
    unsigned short* __restrict__ W1pk, unsigned short* __restrict__ W2pk,
    float* __restrict__ bqkv, unsigned short* __restrict__ xb) {
  const float k2 = 0.25500525551f;  // log2(e)/sqrt(DK)
  int bx = blockIdx.x, t = threadIdx.x;

  if (bx < 192) {
    __shared__ float tile[64][65];
    const float* src;
    int Nsz, ti, tj;
    float scale = 1.0f;
    if (bx < 48) {
      int which = bx >> 4, s = bx & 15;
      src = (which == 0) ? Wq : (which == 1) ? Wk : Wv;
      Nsz = 256; ti = s >> 2; tj = s & 3;
      if (which == 0) scale = k2;
    } else if (bx < 64) {
      int s = bx - 48;
      src = Wo; Nsz = 256; ti = s >> 2; tj = s & 3;
    } else if (bx < 128) {
      int s = bx - 64;
      src = W1; Nsz = 1024; ti = s >> 4; tj = s & 15;
    } else {
      int s = bx - 128;
      src = W2; Nsz = 256; ti = s >> 2; tj = s & 3;
    }
    int row0 = ti * 64, col0 = tj * 64;
    int c = t & 63, rg = t >> 6;
#pragma unroll
    for (int i = 0; i < 16; i++) {
      int rr = rg * 16 + i;
      tile[rr][c] = src[(size_t)(row0 + rr) * Nsz + col0 + c] * scale;
    }
    __syncthreads();

    if (bx < 48) {
      // row-major transposed output (WqkvT)
      unsigned short* dst = WqkvT + (bx >> 4) * 65536;
      int k = t & 63;
#pragma unroll
      for (int i = 0; i < 16; i++) {
        int nn = rg * 16 + i;
        dst[(size_t)(col0 + nn) * 256 + row0 + k] = f2bf(tile[k][nn]);
      }
    } else {
      // fragment-packed output (Wopk / W1pk / W2pk)
      unsigned short* pk = (bx < 64) ? Wopk : (bx < 128) ? W1pk : W2pk;
      int kst_tot = (bx < 128) ? 8 : 32;  // K/32 (Wo,W1: K=256; W2: K=1024)
      int lane2 = t & 63, sub2 = t >> 6;
#pragma unroll
      for (int i = 0; i < 2; i++) {
        int subc = sub2 * 2 + i;          // 0..7
        int ntl = subc >> 1, kst = subc & 1;
        short8 o;
#pragma unroll
        for (int e = 0; e < 8; e++)
          o[e] = (short)f2bf(tile[kst * 32 + (lane2 >> 4) * 8 + e][ntl * 16 + (lane2 & 15)]);
        int ntg = tj * 4 + ntl;
        int ksg = ti * 2 + kst;
        *(short8*)(pk + ((size_t)(ntg * kst_tot + ksg) * 64 + lane2) * 8) = o;
      }
    }
  } else if (bx == 192) {
#pragma unroll
    for (int j = 0; j < 3; j++) {
      int i = j * 256 + t;
      if (i < 768)
        bqkv[i] = (i < 256) ? bq[i] * k2 : (i < 512) ? bk[i - 256] : bv[i - 512];
    }
  } else {
    int i = (bx - 193) * 2048 + t * 8;
    f32x4 f0 = *(const f32x4*)(x + i);
    f32x4 f1 = *(const f32x4*)(x + i + 4);
    short8 o;
#pragma unroll
    for (int e = 0; e < 4; e++) { o[e] = (short)f2bf(f0[e]); o[e + 4] = (short)f2bf(f1[e]); }
    *(short8*)(xb + i) = o;
  }
}

// ---------------- QKV GEMM (BM=64, BN=128) with fragment-scatter epilogue ----
// grid (128, 6) = 768 blocks = 3/CU (even balance; r18's 384 was 1.5/CU).
__global__ __launch_bounds__(256) void k_gemmqkv(const unsigned short* __restrict__ A,
                                                 const unsigned short* __restrict__ Bt,
                                                 const float* __restrict__ bias,
                                                 unsigned short* __restrict__ qb,
                                                 unsigned short* __restrict__ kpk,
                                                 unsigned short* __restrict__ vpk) {
  const int K = 256;
  __shared__ unsigned short Al[64][40];
  __shared__ unsigned short Bl[128][40];
  const int tid = threadIdx.x;
  const int wid = tid >> 6, lane = tid & 63;
  const int lhi = lane >> 4, llo = lane & 15;
  const int wr = wid >> 1, wc = wid & 1;
  const int rowbase = wr * 32, colbase = wc * 64;
  const int bm = blockIdx.x, bn = blockIdx.y;

  f32x4 zero = {0.f, 0.f, 0.f, 0.f};
  f32x4 acc[2][4];
#pragma unroll
  for (int m = 0; m < 2; m++)
#pragma unroll
    for (int n = 0; n < 4; n++) acc[m][n] = zero;

  const int r0 = tid >> 2, c8 = (tid & 3) * 8;
  const unsigned short* A16 = A + (size_t)(bm * 64 + r0) * K + c8;
  const unsigned short* Brow0 = Bt + (size_t)(bn * 128 + r0) * K + c8;
  const unsigned short* Brow1 = Bt + (size_t)(bn * 128 + r0 + 64) * K + c8;

  for (int kb = 0; kb < K; kb += 32) {
    __syncthreads();
    *(short8*)&Al[r0][c8] = *(const short8*)(A16 + kb);
    *(short8*)&Bl[r0][c8] = *(const short8*)(Brow0 + kb);
    *(short8*)&Bl[r0 + 64][c8] = *(const short8*)(Brow1 + kb);
    __syncthreads();
    short8 af[2], bf[4];
#pragma unroll
    for (int m = 0; m < 2; m++) af[m] = *(const short8*)&Al[rowbase + m * 16 + llo][lhi * 8];
#pragma unroll
    for (int n = 0; n < 4; n++) bf[n] = *(const short8*)&Bl[colbase + n * 16 + llo][lhi * 8];
#pragma unroll
    for (int m = 0; m < 2; m++)
#pragma unroll
      for (int n = 0; n < 4; n++)
        acc[m][n] = __builtin_amdgcn_mfma_f32_16x16x32_bf16(af[m], bf[n], acc[m][n], 0, 0, 0);
  }

#pragma unroll
  for (int m = 0; m < 2; m++)
#pragma unroll
    for (int n = 0; n < 4; n++)
#pragma unroll
      for (int r = 0; r < 4; r++) {
        int row = bm * 64 + rowbase + m * 16 + lhi * 4 + r;
        int gcol = bn * 128 + colbase + n * 16 + llo;
        int which = gcol >> 8;  // 0=Q, 1=K, 2=V
        int col0 = gcol & 255;
        float v = acc[m][n][r] + bias[gcol];
        unsigned short bv = f2bf(v);
        int t = row & (S_ - 1), b = row >> 12;
        int h = col0 >> 5;
        if (which == 0) {
          qb[(size_t)row * 256 + col0] = bv;
        } else if (which == 1) {
          int c5 = col0 & 31, jj = (c5 >> 4) & 1, hik = (c5 >> 3) & 1, e = c5 & 7;
          int tile = t >> 6, i = (t >> 5) & 1, l31k = t & 31;
          size_t addr = (((size_t)(b * 8 + h) * 64 + tile) * 4 + i * 2 + jj) * 512 +
                        (hik * 32 + l31k) * 8 + e;
          kpk[addr] = bv;
        } else {
          int d = col0 & 31;
          int x5 = t >> 6, j = (t >> 3) & 7, kk = t & 7;
          size_t addr = (((size_t)(b * 8 + h) * 64 + x5) * 4 + (j >> 1)) * 512 +
                        ((j & 1) * 32 + d) * 8 + kk;
          vpk[addr] = bv;
        }
      }
}

// ---------------- fused Wo: x1b = LN(x + a1*(ctx@Wo + bo)) -------------------
// 256 blocks x 512 thr; 32 rows/block; wave w owns cols w*32..w*32+31.
// Wopk fragment-packed (L2-resident); ctx staged once in LDS.
__global__ __launch_bounds__(512) void k_wo(const unsigned short* __restrict__ ctx,
                                            const unsigned short* __restrict__ Wopk,
                                            const float* __restrict__ bo,
                                            const float* __restrict__ xbase,
                                            const float* __restrict__ alpha,
                                            const float* __restrict__ g,
                                            const float* __restrict__ be,
                                            unsigned short* __restrict__ x1b) {
  __shared__ unsigned short Ax[32][268];
  __shared__ float psum[32][8], psq[32][8];
  const int tid = threadIdx.x;
  const int w = tid >> 6, lane = tid & 63;
  const int lhi = lane >> 4, llo = lane & 15;
  const int row0 = blockIdx.x * 32;

  {
    int r = tid >> 4, c0 = (tid & 15) * 16;
    const unsigned short* src = ctx + (size_t)(row0 + r) * 256 + c0;
    *(short8*)&Ax[r][c0] = *(const short8*)(src);
    *(short8*)&Ax[r][c0 + 8] = *(const short8*)(src + 8);
  }
  __syncthreads();

  f32x4 zero4 = {0.f, 0.f, 0.f, 0.f};
  f32x4 acc[2][2];
#pragma unroll
  for (int m = 0; m < 2; m++)
#pragma unroll
    for (int n = 0; n < 2; n++) acc[m][n] = zero4;

  const unsigned short* wobase = Wopk + (size_t)(w * 2) * 4096 + lane * 8;
#pragma unroll
  for (int kb = 0; kb < 8; ++kb) {
    short8 af0 = *(const short8*)&Ax[llo][kb * 32 + lhi * 8];
    short8 af1 = *(const short8*)&Ax[16 + llo][kb * 32 + lhi * 8];
    short8 bf0 = *(const short8*)(wobase + kb * 512);
    short8 bf1 = *(const short8*)(wobase + 4096 + kb * 512);
    acc[0][0] = __builtin_amdgcn_mfma_f32_16x16x32_bf16(af0, bf0, acc[0][0], 0, 0, 0);
    acc[0][1] = __builtin_amdgcn_mfma_f32_16x16x32_bf16(af0, bf1, acc[0][1], 0, 0, 0);
    acc[1][0] = __builtin_amdgcn_mfma_f32_16x16x32_bf16(af1, bf0, acc[1][0], 0, 0, 0);
    acc[1][1] = __builtin_amdgcn_mfma_f32_16x16x32_bf16(af1, bf1, acc[1][1], 0, 0, 0);
  }

  const float a = alpha[0];
#pragma unroll
  for (int m = 0; m < 2; m++)
#pragma unroll
    for (int r = 0; r < 4; r++) {
      int lrow = m * 16 + lhi * 4 + r;
      size_t grow = (size_t)(row0 + lrow);
      float s = 0.f, q = 0.f;
#pragma unroll
      for (int n = 0; n < 2; n++) {
        int col = w * 32 + n * 16 + llo;
        float v = acc[m][n][r] + bo[col];
        float xv = xbase[grow * 256 + col];
        float rr = fmaf(a, v, xv);
        acc[m][n][r] = rr;
        s += rr;
        q = fmaf(rr, rr, q);
      }
#pragma unroll
      for (int off = 1; off < 16; off <<= 1) {
        s += __shfl_xor(s, off);
        q += __shfl_xor(q, off);
      }
      if (llo == 0) { psum[lrow][w] = s; psq[lrow][w] = q; }
    }
  __syncthreads();
#pragma unroll
  for (int m = 0; m < 2; m++)
#pragma unroll
    for (int r = 0; r < 4; r++) {
      int lrow = m * 16 + lhi * 4 + r;
      size_t grow = (size_t)(row0 + lrow);
      float S = 0.f, Q = 0.f;
#pragma unroll
      for (int j = 0; j < 8; j++) { S += psum[lrow][j]; Q += psq[lrow][j]; }
      float mu = S * (1.0f / 256.0f);
      float var = Q * (1.0f / 256.0f) - mu * mu;
      float rs = rsqrtf(var + 1e-5f);
#pragma unroll
      for (int n = 0; n < 2; n++) {
        int col = w * 32 + n * 16 + llo;
        x1b[grow * 256 + col] = f2bf((acc[m][n][r] - mu) * rs * g[col] + be[col]);
      }
    }
}

// ---------------- fused FFN: out = LN(x1b + a2*(GELU(x1b@W1+b1)@W2+b2)) ------
__global__ __launch_bounds__(512) void k_ffn(const unsigned short* __restrict__ x1b,
                                             const unsigned short* __restrict__ W1pk,
                                             const float* __restrict__ b1,
                                             const unsigned short* __restrict__ W2pk,
                                             const float* __restrict__ b2,
                                             const float* __restrict__ alpha,
                                             const float* __restrict__ g,
                                             const float* __restrict__ be,
                                             float* __restrict__ out) {
  __shared__ unsigned short Ax[32][268];
  __shared__ unsigned short Hl[32][268];
  __shared__ float psum[32][8], psq[32][8];
  const int tid = threadIdx.x;
  const int w = tid >> 6, lane = tid & 63;
  const int lhi = lane >> 4, llo = lane & 15;
  const int row0 = blockIdx.x * 32;

  {
    int r = tid >> 4, c0 = (tid & 15) * 16;
    const unsigned short* src = x1b + (size_t)(row0 + r) * 256 + c0;
    *(short8*)&Ax[r][c0] = *(const short8*)(src);
    *(short8*)&Ax[r][c0 + 8] = *(const short8*)(src + 8);
  }
  __syncthreads();

  f32x4 zero4 = {0.f, 0.f, 0.f, 0.f};
  f32x4 acc2[2][2];
#pragma unroll
  for (int m = 0; m < 2; m++)
#pragma unroll
    for (int n = 0; n < 2; n++) acc2[m][n] = zero4;

  for (int c = 0; c < 4; ++c) {
    f32x4 acc1[2][2];
#pragma unroll
    for (int m = 0; m < 2; m++)
#pragma unroll
      for (int n = 0; n < 2; n++) acc1[m][n] = zero4;
    const unsigned short* w1base = W1pk + (size_t)(c * 16 + w * 2) * 4096 + lane * 8;
#pragma unroll
    for (int kb = 0; kb < 8; ++kb) {
      short8 af0 = *(const short8*)&Ax[llo][kb * 32 + lhi * 8];
      short8 af1 = *(const short8*)&Ax[16 + llo][kb * 32 + lhi * 8];
      short8 bf0 = *(const short8*)(w1base + kb * 512);
      short8 bf1 = *(const short8*)(w1base + 4096 + kb * 512);
      acc1[0][0] = __builtin_amdgcn_mfma_f32_16x16x32_bf16(af0, bf0, acc1[0][0], 0, 0, 0);
      acc1[0][1] = __builtin_amdgcn_mfma_f32_16x16x32_bf16(af0, bf1, acc1[0][1], 0, 0, 0);
      acc1[1][0] = __builtin_amdgcn_mfma_f32_16x16x32_bf16(af1, bf0, acc1[1][0], 0, 0, 0);
      acc1[1][1] = __builtin_amdgcn_mfma_f32_16x16x32_bf16(af1, bf1, acc1[1][1], 0, 0, 0);
    }
    __syncthreads();  // S1: all waves finished reading Hl (prev chunk GEMM2)
#pragma unroll
    for (int m = 0; m < 2; m++)
#pragma unroll
      for (int n = 0; n < 2; n++)
#pragma unroll
        for (int r = 0; r < 4; r++) {
          int col = w * 32 + n * 16 + llo;
          float v = acc1[m][n][r] + b1[c * 256 + col];
          Hl[m * 16 + lhi * 4 + r][col] = f2bf(gelu_fast(v));
        }
    __syncthreads();  // S2: Hl visible
    const unsigned short* w2base = W2pk + (size_t)(w * 2) * 16384 + (size_t)(c * 8) * 512 + lane * 8;
#pragma unroll
    for (int kk = 0; kk < 8; ++kk) {
      short8 a0 = *(const short8*)&Hl[llo][kk * 32 + lhi * 8];
      short8 a1 = *(const short8*)&Hl[16 + llo][kk * 32 + lhi * 8];
      short8 bf0 = *(const short8*)(w2base + kk * 512);
      short8 bf1 = *(const short8*)(w2base + 16384 + kk * 512);
      acc2[0][0] = __builtin_amdgcn_mfma_f32_16x16x32_bf16(a0, bf0, acc2[0][0], 0, 0, 0);
      acc2[0][1] = __builtin_amdgcn_mfma_f32_16x16x32_bf16(a0, bf1, acc2[0][1], 0, 0, 0);
      acc2[1][0] = __builtin_amdgcn_mfma_f32_16x16x32_bf16(a1, bf0, acc2[1][0], 0, 0, 0);
      acc2[1][1] = __builtin_amdgcn_mfma_f32_16x16x32_bf16(a1, bf1, acc2[1][1], 0, 0, 0);
    }
  }

  const float a = alpha[0];
#pragma unroll
  for (int m = 0; m < 2; m++)
#pragma unroll
    for (int r = 0; r < 4; r++) {
      int lrow = m * 16 + lhi * 4 + r;
      float s = 0.f, q = 0.f;
#pragma unroll
      for (int n = 0; n < 2; n++) {
        int col = w * 32 + n * 16 + llo;
        float v = acc2[m][n][r] + b2[col];
        float xv = bf2f(Ax[lrow][col]);
        float rr = fmaf(a, v, xv);
        acc2[m][n][r] = rr;
        s += rr;
        q = fmaf(rr, rr, q);
      }
#pragma unroll
      for (int off = 1; off < 16; off <<= 1) {
        s += __shfl_xor(s, off);
        q += __shfl_xor(q, off);
      }
      if (llo == 0) { psum[lrow][w] = s; psq[lrow][w] = q; }
    }
  __syncthreads();
#pragma unroll
  for (int m = 0; m < 2; m++)
#pragma unroll
    for (int r = 0; r < 4; r++) {
      int lrow = m * 16 + lhi * 4 + r;
      size_t grow = (size_t)(row0 + lrow);
      float S = 0.f, Q = 0.f;
#pragma unroll
      for (int j = 0; j < 8; j++) { S += psum[lrow][j]; Q += psq[lrow][j]; }
      float mu = S * (1.0f / 256.0f);
      float var = Q * (1.0f / 256.0f) - mu * mu;
      float rs = rsqrtf(var + 1e-5f);
#pragma unroll
      for (int n = 0; n < 2; n++) {
        int col = w * 32 + n * 16 + llo;
        out[grow * 256 + col] = (acc2[m][n][r] - mu) * rs * g[col] + be[col];
      }
    }
}

// ---------------- flash attention: 4 waves = 4 key-quarters, 64 q-rows/wave --
// (round-17 version: explicit double-buffered K/V registers, verified stable)
__global__ __launch_bounds__(256, 2) void k_attn(const unsigned short* __restrict__ qbuf,
                                                 const unsigned short* __restrict__ kpk,
                                                 const unsigned short* __restrict__ vpk,
                                                 const int* __restrict__ mask,
                                                 unsigned short* __restrict__ ctx) {
  __shared__ float accS[4][64][32];  // 32 KB
  __shared__ float lS[4][64];
  const int tid = threadIdx.x;
  const int lane = tid & 63;
  const int w = tid >> 6;            // key quarter
  const int l31 = lane & 31, hi = lane >> 5;
  const int q0 = blockIdx.x * 64;
  const int h = blockIdx.y, b = blockIdx.z;
  const size_t bS = (size_t)b * S_;

  const unsigned short* QpA = qbuf + (bS + q0 + l31) * 256 + h * DK_ + hi * 8;
  short8 qa0 = *(const short8*)QpA;
  short8 qa1 = *(const short8*)(QpA + 16);
  const unsigned short* QpB = QpA + 32 * 256;
  short8 qb0 = *(const short8*)QpB;
  short8 qb1 = *(const short8*)(QpB + 16);

  const size_t fragbase = ((size_t)(b * H_ + h) * 64 + w * 16) * 2048 + lane * 8;
  const unsigned short* kp = kpk + fragbase;
  const unsigned short* vp = vpk + fragbase;
  const int* mp = mask + bS + w * 1024 + lane;

  f32x16 accA, accB, laccA, laccB;
#pragma unroll
  for (int r = 0; r < 16; r++) { accA[r] = 0.f; accB[r] = 0.f; laccA[r] = 0.f; laccB[r] = 0.f; }
  const f32x16 zz = accA;
  short8 ones;
#pragma unroll
  for (int e = 0; e < 8; e++) ones[e] = (short)0x3F80;

  short8 kA[4], vA[4], kB[4], vB[4];
  unsigned int pk0[8], pk1[8];
  f32x16 s0, s1;
  int tcur = 0;
  int mvC, mvN;

#define LDK(DST) { DST[0] = *(const short8*)(kp); DST[1] = *(const short8*)(kp + 512); \
                   DST[2] = *(const short8*)(kp + 1024); DST[3] = *(const short8*)(kp + 1536); kp += 2048; }
#define LDV(DST) { DST[0] = *(const short8*)(vp); DST[1] = *(const short8*)(vp + 512); \
                   DST[2] = *(const short8*)(vp + 1024); DST[3] = *(const short8*)(vp + 1536); vp += 2048; }
#define QKM(KF, qx0, qx1) {                                                      \
    s0 = __builtin_amdgcn_mfma_f32_32x32x16_bf16(KF[0], qx0, zz, 0, 0, 0);       \
    s1 = __builtin_amdgcn_mfma_f32_32x32x16_bf16(KF[2], qx0, zz, 0, 0, 0);       \
    s0 = __builtin_amdgcn_mfma_f32_32x32x16_bf16(KF[1], qx1, s0, 0, 0, 0);       \
    s1 = __builtin_amdgcn_mfma_f32_32x32x16_bf16(KF[3], qx1, s1, 0, 0, 0);       \
  }
#define EXPM(bal) {                                                              \
    if (__builtin_expect((bal) != ~0ull, 0)) {                                   \
      _Pragma("unroll") for (int r = 0; r < 16; r++) {                           \
        int tt = (r & 3) + 8 * (r >> 2) + 4 * hi;                                \
        if (!(((bal) >> tt) & 1)) s0[r] = -3e38f;                                \
        if (!(((bal) >> (tt + 32)) & 1)) s1[r] = -3e38f;                         \
      }                                                                          \
    }                                                                            \
    _Pragma("unroll") for (int r = 0; r < 16; r++) {                             \
      s0[r] = __builtin_amdgcn_exp2f(s0[r]);                                     \
      s1[r] = __builtin_amdgcn_exp2f(s1[r]);                                     \
    }                                                                            \
    _Pragma("unroll") for (int j = 0; j < 8; j++) {                              \
      asm("v_cvt_pk_bf16_f32 %0, %1, %2" : "=v"(pk0[j]) : "v"(s0[2*j]), "v"(s0[2*j+1])); \
      asm("v_cvt_pk_bf16_f32 %0, %1, %2" : "=v"(pk1[j]) : "v"(s1[2*j]), "v"(s1[2*j+1])); \
    }                                                                            \
  }
#define PVM(VF, accX, laccX) {                                                   \
    __builtin_amdgcn_s_setprio(1);                                               \
    _Pragma("unroll") for (int kk = 0; kk < 4; kk++) {                           \
      unsigned int* pk = (kk < 2) ? pk0 : pk1;                                   \
      int base = (kk & 1) * 4;                                                   \
      auto r02 = __builtin_amdgcn_permlane32_swap(pk[base], pk[base + 2], false, false);     \
      auto r13 = __builtin_amdgcn_permlane32_swap(pk[base + 1], pk[base + 3], false, false); \
      short8 pfr = u32x4_to_s8(r02[0], r13[0], r02[1], r13[1]);                  \
      accX = __builtin_amdgcn_mfma_f32_32x32x16_bf16(pfr, VF[kk], accX, 0, 0, 0);\
      laccX = __builtin_amdgcn_mfma_f32_32x32x16_bf16(pfr, ones, laccX, 0, 0, 0);\
    }                                                                            \
    __builtin_amdgcn_s_setprio(0);                                               \
  }
#define TILESTEP(KC, VC, KN, VN) {                                               \
    unsigned long long bal = __ballot(mvC != 0);                                 \
    QKM(KC, qa0, qa1);                                                           \
    LDK(KN);                                                                     \
    EXPM(bal);                                                                   \
    PVM(VC, accA, laccA);                                                        \
    QKM(KC, qb0, qb1);                                                           \
    LDV(VN);                                                                     \
    EXPM(bal);                                                                   \
    PVM(VC, accB, laccB);                                                        \
    mvC = mvN;                                                                   \
    tcur++;                                                                      \
    mvN = mp[(tcur + 1 < 16 ? tcur + 1 : 15) * 64];                              \
  }

  LDK(kA);   // K(0)
  LDV(vA);   // V(0)
  mvC = mp[0];
  mvN = mp[64];

  for (int it = 0; it < 8; ++it) {
    TILESTEP(kA, vA, kB, vB);
    TILESTEP(kB, vB, kA, vA);
  }

  // 4-way merge across key-quarters (plain sums; no-max softmax)
#pragma unroll
  for (int r = 0; r < 16; r++) {
    int q = (r & 3) + 8 * (r >> 2) + 4 * hi;
    accS[w][q][l31] = accA[r];
    accS[w][q + 32][l31] = accB[r];
  }
  if (l31 == 0) {
#pragma unroll
    for (int r = 0; r < 16; r++) {
      int q = (r & 3) + 8 * (r >> 2) + 4 * hi;
      lS[w][q] = laccA[r];
      lS[w][q + 32] = laccB[r];
    }
  }
  __syncthreads();
#pragma unroll
  for (int i = 0; i < 8; i++) {
    int e = tid + 256 * i;
    int q = e >> 5, d = e & 31;
    float o = accS[0][q][d] + accS[1][q][d] + accS[2][q][d] + accS[3][q][d];
    float L = lS[0][q] + lS[1][q] + lS[2][q] + lS[3][q];
    ctx[(bS + q0 + q) * (size_t)D_ + h * DK_ + d] = f2bf(o / L);
  }
#undef LDK
#undef LDV
#undef QKM
#undef EXPM
#undef PVM
#undef TILESTEP
}

extern "C" void kernel_launch(void* const* d_in, const int* in_sizes, int n_in,
                              void* d_out, int out_size, void* d_ws, size_t ws_size,
                              hipStream_t stream) {
  const float* x   = (const float*)d_in[0];
  const int* mask  = (const int*)d_in[1];
  const float* Wq  = (const float*)d_in[2];
  const float* bq  = (const float*)d_in[3];
  const float* Wk  = (const float*)d_in[4];
  const float* bk  = (const float*)d_in[5];
  const float* Wv  = (const float*)d_in[6];
  const float* bv  = (const float*)d_in[7];
  const float* Wo  = (const float*)d_in[8];
  const float* bo  = (const float*)d_in[9];
  const float* W1  = (const float*)d_in[10];
  const float* b1  = (const float*)d_in[11];
  const float* W2  = (const float*)d_in[12];
  const float* b2  = (const float*)d_in[13];
  const float* g1  = (const float*)d_in[14];
  const float* be1 = (const float*)d_in[15];
  const float* g2  = (const float*)d_in[16];
  const float* be2 = (const float*)d_in[17];
  const float* a1  = (const float*)d_in[18];
  const float* a2  = (const float*)d_in[19];
  float* out = (float*)d_out;

  char* ws = (char*)d_ws;
  const size_t MB = 1024 * 1024;
  unsigned short* qb  = (unsigned short*)(ws + 0);        // 4 MB
  unsigned short* kpk = (unsigned short*)(ws + 5 * MB);   // 4 MB (+1 MB slack)
  unsigned short* vpk = (unsigned short*)(ws + 10 * MB);  // 4 MB (+1 MB slack)
  unsigned short* ctx = (unsigned short*)(ws + 15 * MB);  // 4 MB
  unsigned short* x1b = (unsigned short*)(ws + 19 * MB);  // 4 MB
  unsigned short* WqkvT = (unsigned short*)(ws + 40 * MB);               // 384 KB
  unsigned short* Wopk  = (unsigned short*)(ws + 40 * MB + 512 * 1024);  // 128 KB
  unsigned short* W1pk  = (unsigned short*)(ws + 41 * MB);               // 512 KB
  unsigned short* W2pk  = (unsigned short*)(ws + 41 * MB + 512 * 1024);  // 512 KB
  float* bqkv           = (float*)(ws + 42 * MB);                        // 3 KB
  unsigned short* xb    = (unsigned short*)(ws + 43 * MB);               // 4 MB

  const int NTOK = B_ * S_;  // 8192

  k_prepw<<<dim3(1217), 256, 0, stream>>>(Wq, Wk, Wv, Wo, W1, W2, bq, bk, bv, x,
                                          WqkvT, Wopk, W1pk, W2pk, bqkv, xb);

  k_gemmqkv<<<dim3(128, 6), 256, 0, stream>>>(xb, WqkvT, bqkv, qb, kpk, vpk);

  k_attn<<<dim3(S_ / 64, H_, B_), 256, 0, stream>>>(qb, kpk, vpk, mask, ctx);

  // Wo GEMM + residual(x) + LN1 -> x1b (bf16)
  k_wo<<<dim3(NTOK / 32), 512, 0, stream>>>(ctx, Wopk, bo, x, a1, g1, be1, x1b);

  // fused FFN + residual + LN2 -> out (f32)
  k_ffn<<<dim3(NTOK / 32), 512, 0, stream>>>(x1b, W1pk, b1, W2pk, b2, a2, g2, be2, out);
}